// Round 1
// baseline (584.906 us; speedup 1.0000x reference)
//
#include <hip/hip_runtime.h>
#include <stdint.h>
#include <stddef.h>

// ISNNet: x[:,0]=x0; x[:,t] = x[:,t-1] @ eW.T + I[:,t-1] @ W_inv_eW.T
// B=64, T=2048, D=256.  All matmuls use 3-term compensated bf16 MFMA
// (hi/lo split, f32 accumulate) to hit f32-level accuracy.

#define BATCH 64
#define TLEN 2048
#define DDIM 256
#define CHUNK 64
#define NCHUNK 32

typedef __attribute__((ext_vector_type(8))) short short8;
typedef __attribute__((ext_vector_type(4))) float f32x4;

#define MFMA16(a, b, c) __builtin_amdgcn_mfma_f32_16x16x32_bf16((a), (b), (c), 0, 0, 0)

__device__ __forceinline__ uint16_t f2bf(float f) {
  union { float f; uint32_t u; } v; v.f = f;
  return (uint16_t)((v.u + 0x7fffu + ((v.u >> 16) & 1u)) >> 16);  // RNE
}
__device__ __forceinline__ float bf2f(uint16_t h) {
  union { uint32_t u; float f; } v; v.u = ((uint32_t)h) << 16;
  return v.f;
}

// split 8 f32 into hi/lo bf16 fragments
__device__ __forceinline__ void split8(const float* fv, short8& hi, short8& lo) {
#pragma unroll
  for (int j = 0; j < 8; ++j) {
    uint16_t hb = f2bf(fv[j]);
    hi[j] = (short)hb;
    lo[j] = (short)f2bf(fv[j] - bf2f(hb));
  }
}

// raw barrier: waits LDS ops but NOT outstanding global loads (keeps u-prefetch in flight)
__device__ __forceinline__ void wg_barrier() {
  __builtin_amdgcn_sched_barrier(0);
  asm volatile("s_waitcnt lgkmcnt(0)" ::: "memory");
  __builtin_amdgcn_s_barrier();
  asm volatile("" ::: "memory");
  __builtin_amdgcn_sched_barrier(0);
}

// ---------------- workspace layout (bytes) ----------------
#define WS_A_HI   (0)
#define WS_A_LO   (128 * 1024)
#define WS_WB_HI  (256 * 1024)
#define WS_WB_LO  (384 * 1024)
#define WS_MBUF   (512 * 1024)   // f32 [256][256]
#define WS_M_HI   (768 * 1024)
#define WS_M_LO   (896 * 1024)
#define WS_M2F    (1024 * 1024)  // f32
#define WS_M2_HI  (1280 * 1024)
#define WS_M2_LO  (1408 * 1024)
#define WS_M3F    (1536 * 1024)  // f32
#define WS_M3_HI  (1792 * 1024)
#define WS_M3_LO  (1920 * 1024)
#define WS_S      (2048 * 1024)  // f32 [32][64][256] = 2MB
#define WS_Y      (4096 * 1024)  // f32 [32][64][256] = 2MB
// total 6MB

// ---------------- k_split: hi/lo decompose eW, W_inv_eW ----------------
// A_t[n][k] = A[k][n] = eW[n][k]  -> flat copy of eW.   Same for Wb from W_inv_eW.
__global__ void k_split(const float* __restrict__ eW, const float* __restrict__ Wi,
                        uint16_t* __restrict__ Ah, uint16_t* __restrict__ Al,
                        uint16_t* __restrict__ Wh, uint16_t* __restrict__ Wl) {
  int idx = blockIdx.x * blockDim.x + threadIdx.x;
  if (idx < 65536) {
    float v = eW[idx];
    uint16_t h = f2bf(v);
    Ah[idx] = h;
    Al[idx] = f2bf(v - bf2f(h));
  } else if (idx < 131072) {
    int i = idx - 65536;
    float v = Wi[i];
    uint16_t h = f2bf(v);
    Wh[i] = h;
    Wl[i] = f2bf(v - bf2f(h));
  }
}

// ---------------- k_u: u = I @ Wb, stored into d_out at time t+1 ----------------
// tiles: 64 b * 128 ttile (16 t-rows) = 8192; grid-stride over 1024 WGs.
__global__ __launch_bounds__(512, 2) void k_u(const float* __restrict__ I,
                                              const uint16_t* __restrict__ Wh,
                                              const uint16_t* __restrict__ Wl,
                                              float* __restrict__ out) {
  const int tid = threadIdx.x;
  const int w = tid >> 6, l = tid & 63, l15 = l & 15, quad = l >> 4;
  const int ns = w * 32;
  __shared__ __align__(16) float sI[4096];  // 16 rows x 256, swizzled

  short8 bh[2][8], bl[2][8];
#pragma unroll
  for (int nf = 0; nf < 2; ++nf)
#pragma unroll
    for (int ks = 0; ks < 8; ++ks) {
      const int off = (ns + nf * 16 + l15) * 256 + ks * 32 + quad * 8;
      bh[nf][ks] = *reinterpret_cast<const short8*>(Wh + off);
      bl[nf][ks] = *reinterpret_cast<const short8*>(Wl + off);
    }

  for (int tl = blockIdx.x; tl < 8192; tl += 1024) {
    const int b = tl >> 7, tt = tl & 127;
    __syncthreads();  // protect LDS vs previous tile readers
    const f32x4* src = reinterpret_cast<const f32x4*>(I + ((size_t)b * TLEN + tt * 16) * DDIM);
#pragma unroll
    for (int it = 0; it < 2; ++it) {
      int fi = tid + it * 512;
      int row = fi >> 6;
      uint32_t byte = (uint32_t)(fi * 16) ^ (uint32_t)((row & 7) << 4);
      *reinterpret_cast<f32x4*>(reinterpret_cast<char*>(sI) + byte) = src[fi];
    }
    __syncthreads();
    f32x4 acc0 = {0.f, 0.f, 0.f, 0.f}, acc1 = {0.f, 0.f, 0.f, 0.f};
#pragma unroll
    for (int ks = 0; ks < 8; ++ks) {
      int kb = ks * 32 + quad * 8;
      uint32_t sw = (uint32_t)((l15 & 7) << 4);
      uint32_t b0 = (uint32_t)(l15 * 1024 + kb * 4) ^ sw;
      uint32_t b1 = (uint32_t)(l15 * 1024 + kb * 4 + 16) ^ sw;
      f32x4 f0 = *reinterpret_cast<const f32x4*>(reinterpret_cast<const char*>(sI) + b0);
      f32x4 f1 = *reinterpret_cast<const f32x4*>(reinterpret_cast<const char*>(sI) + b1);
      float fv[8] = {f0[0], f0[1], f0[2], f0[3], f1[0], f1[1], f1[2], f1[3]};
      short8 ah, al8;
      split8(fv, ah, al8);
      acc0 = MFMA16(ah, bh[0][ks], acc0);
      acc0 = MFMA16(al8, bh[0][ks], acc0);
      acc0 = MFMA16(ah, bl[0][ks], acc0);
      acc1 = MFMA16(ah, bh[1][ks], acc1);
      acc1 = MFMA16(al8, bh[1][ks], acc1);
      acc1 = MFMA16(ah, bl[1][ks], acc1);
    }
#pragma unroll
    for (int nf = 0; nf < 2; ++nf)
#pragma unroll
      for (int r = 0; r < 4; ++r) {
        int trow = tt * 16 + quad * 4 + r;
        if (trow <= TLEN - 2) {  // u_t lives at location t+1; t <= 2046
          int col = ns + nf * 16 + l15;
          out[((size_t)b * TLEN + trow + 1) * DDIM + col] = (nf ? acc1 : acc0)[r];
        }
      }
  }
}

// ---------------- k_scan: in-chunk recurrence ----------------
// pass 1: from zero state -> S_c (+ 16 E-WGs propagate identity -> M = A^64)
// pass 2: from Y_c -> write outputs
__global__ __launch_bounds__(512, 2) void k_scan(const int pass,
                                                 const uint16_t* __restrict__ Ah,
                                                 const uint16_t* __restrict__ Al,
                                                 float* __restrict__ xu,  // d_out: u in (shifted), x out
                                                 const float* __restrict__ Y,
                                                 float* __restrict__ S,
                                                 float* __restrict__ Mbuf,
                                                 uint16_t* __restrict__ Mh,
                                                 uint16_t* __restrict__ Ml) {
  const int tid = threadIdx.x;
  const int w = tid >> 6, l = tid & 63, l15 = l & 15, quad = l >> 4;
  const int ns = w * 32;
  bool isE = false;
  int c = 0, rg = 0, eb = 0;
  if (pass == 1 && blockIdx.x >= 128) {
    isE = true;
    eb = blockIdx.x - 128;
  } else {
    c = blockIdx.x >> 2;
    rg = blockIdx.x & 3;
  }
  __shared__ __align__(16) uint16_t sh[2][4096];
  __shared__ __align__(16) uint16_t sl[2][4096];

  // A fragments resident in registers (per-wave 32-col slice), 128 VGPR
  short8 fAh[2][8], fAl[2][8];
#pragma unroll
  for (int nf = 0; nf < 2; ++nf)
#pragma unroll
    for (int ks = 0; ks < 8; ++ks) {
      const int off = (ns + nf * 16 + l15) * 256 + ks * 32 + quad * 8;
      fAh[nf][ks] = *reinterpret_cast<const short8*>(Ah + off);
      fAl[nf][ks] = *reinterpret_cast<const short8*>(Al + off);
    }

  // init state (buf 0)
  for (int i = tid; i < 4096; i += 512) {
    int row = i >> 8, k = i & 255;
    float v;
    if (isE)
      v = (k == eb * 16 + row) ? 1.0f : 0.0f;
    else if (pass == 1)
      v = 0.0f;
    else {
      v = Y[((size_t)c * 64 + rg * 16 + row) * DDIM + k];
      if (c == 0) xu[((size_t)(rg * 16 + row) * TLEN) * DDIM + k] = v;  // x[:,0,:] = x0
    }
    uint16_t hb = f2bf(v);
    uint16_t lb = f2bf(v - bf2f(hb));
    uint32_t byte = (uint32_t)(row * 512 + k * 2) ^ (uint32_t)((row & 7) << 4);
    *(uint16_t*)((char*)sh[0] + byte) = hb;
    *(uint16_t*)((char*)sl[0] + byte) = lb;
  }
  __syncthreads();

  const int t0 = c * CHUNK;
  const int nsteps = isE ? 64 : ((t0 + CHUNK <= TLEN - 1) ? CHUNK : (TLEN - 1 - t0));

  float u0[8], u1[8], fin[8];
#pragma unroll
  for (int j = 0; j < 8; ++j) { u0[j] = 0.f; u1[j] = 0.f; fin[j] = 0.f; }

  auto issue_u = [&](int i, float (&dst)[8]) {
    if (isE || i > nsteps) return;
#pragma unroll
    for (int nf = 0; nf < 2; ++nf)
#pragma unroll
      for (int r = 0; r < 4; ++r) {
        int b = rg * 16 + quad * 4 + r;
        dst[nf * 4 + r] = xu[((size_t)b * TLEN + t0 + i) * DDIM + ns + nf * 16 + l15];
      }
  };
  issue_u(1, u0);
  issue_u(2, u1);

  int p = 0;
  auto step = [&](int i, float (&ucur)[8]) {
    f32x4 acc0 = {0.f, 0.f, 0.f, 0.f}, acc1 = {0.f, 0.f, 0.f, 0.f};
#pragma unroll
    for (int ks = 0; ks < 8; ++ks) {
      uint32_t byte = (uint32_t)(l15 * 512 + ks * 64 + quad * 16) ^ (uint32_t)((l15 & 7) << 4);
      short8 xh = *reinterpret_cast<const short8*>((const char*)sh[p] + byte);
      short8 xl = *reinterpret_cast<const short8*>((const char*)sl[p] + byte);
      acc0 = MFMA16(xh, fAh[0][ks], acc0);
      acc0 = MFMA16(xl, fAh[0][ks], acc0);
      acc0 = MFMA16(xh, fAl[0][ks], acc0);
      acc1 = MFMA16(xh, fAh[1][ks], acc1);
      acc1 = MFMA16(xl, fAh[1][ks], acc1);
      acc1 = MFMA16(xh, fAl[1][ks], acc1);
    }
#pragma unroll
    for (int nf = 0; nf < 2; ++nf)
#pragma unroll
      for (int r = 0; r < 4; ++r) {
        float v = (nf ? acc1 : acc0)[r];
        if (!isE) v += ucur[nf * 4 + r];
        fin[nf * 4 + r] = v;
      }
    if (pass == 2) {
#pragma unroll
      for (int nf = 0; nf < 2; ++nf)
#pragma unroll
        for (int r = 0; r < 4; ++r) {
          int b = rg * 16 + quad * 4 + r;
          xu[((size_t)b * TLEN + t0 + i) * DDIM + ns + nf * 16 + l15] = fin[nf * 4 + r];
        }
    }
    issue_u(i + 2, ucur);  // prefetch depth 2
    if (i < nsteps) {
#pragma unroll
      for (int nf = 0; nf < 2; ++nf)
#pragma unroll
        for (int r = 0; r < 4; ++r) {
          int row = quad * 4 + r, col = ns + nf * 16 + l15;
          float v = fin[nf * 4 + r];
          uint16_t hb = f2bf(v);
          uint16_t lb = f2bf(v - bf2f(hb));
          uint32_t byte = (uint32_t)(row * 512 + col * 2) ^ (uint32_t)((row & 7) << 4);
          *(uint16_t*)((char*)sh[p ^ 1] + byte) = hb;
          *(uint16_t*)((char*)sl[p ^ 1] + byte) = lb;
        }
      wg_barrier();
      p ^= 1;
    }
  };

  for (int i = 1; i + 1 <= nsteps; i += 2) {
    step(i, u0);
    step(i + 1, u1);
  }
  if (nsteps & 1) step(nsteps, u0);

  if (pass == 1) {
#pragma unroll
    for (int nf = 0; nf < 2; ++nf)
#pragma unroll
      for (int r = 0; r < 4; ++r) {
        int row = quad * 4 + r, col = ns + nf * 16 + l15;
        float v = fin[nf * 4 + r];
        if (isE) {
          int R = eb * 16 + row;
          Mbuf[(size_t)R * 256 + col] = v;
          uint16_t hb = f2bf(v);
          Mh[(size_t)col * 256 + R] = hb;
          Ml[(size_t)col * 256 + R] = f2bf(v - bf2f(hb));
        } else {
          S[((size_t)c * 64 + rg * 16 + row) * DDIM + col] = v;
        }
      }
  }
}

// ---------------- k_mm256: OUT = Af @ B  (256x256, one WG) ----------------
// Af f32 row-major; B given as hi/lo n-major (B_t[n][k]); writes f32 + n-major hi/lo.
__global__ __launch_bounds__(512, 2) void k_mm256(const float* __restrict__ Af,
                                                  const uint16_t* __restrict__ Bh,
                                                  const uint16_t* __restrict__ Bl,
                                                  float* __restrict__ Of,
                                                  uint16_t* __restrict__ Oh,
                                                  uint16_t* __restrict__ Ol) {
  const int tid = threadIdx.x;
  const int w = tid >> 6, l = tid & 63, l15 = l & 15, quad = l >> 4;
  const int ns = w * 32;
  f32x4 acc[16][2];
#pragma unroll
  for (int mf = 0; mf < 16; ++mf)
#pragma unroll
    for (int nf = 0; nf < 2; ++nf) acc[mf][nf] = {0.f, 0.f, 0.f, 0.f};

#pragma unroll 1
  for (int mf = 0; mf < 16; ++mf) {
#pragma unroll
    for (int ks = 0; ks < 8; ++ks) {
      const float* ap = Af + (size_t)(mf * 16 + l15) * 256 + ks * 32 + quad * 8;
      f32x4 f0 = *reinterpret_cast<const f32x4*>(ap);
      f32x4 f1 = *reinterpret_cast<const f32x4*>(ap + 4);
      float fv[8] = {f0[0], f0[1], f0[2], f0[3], f1[0], f1[1], f1[2], f1[3]};
      short8 ah, al8;
      split8(fv, ah, al8);
#pragma unroll
      for (int nf = 0; nf < 2; ++nf) {
        const int off = (ns + nf * 16 + l15) * 256 + ks * 32 + quad * 8;
        short8 bhf = *reinterpret_cast<const short8*>(Bh + off);
        short8 blf = *reinterpret_cast<const short8*>(Bl + off);
        acc[mf][nf] = MFMA16(ah, bhf, acc[mf][nf]);
        acc[mf][nf] = MFMA16(al8, bhf, acc[mf][nf]);
        acc[mf][nf] = MFMA16(ah, blf, acc[mf][nf]);
      }
    }
  }
#pragma unroll
  for (int mf = 0; mf < 16; ++mf)
#pragma unroll
    for (int nf = 0; nf < 2; ++nf)
#pragma unroll
      for (int r = 0; r < 4; ++r) {
        int row = mf * 16 + quad * 4 + r;
        int col = ns + nf * 16 + l15;
        float v = acc[mf][nf][r];
        Of[(size_t)row * 256 + col] = v;
        uint16_t hb = f2bf(v);
        Oh[(size_t)col * 256 + row] = hb;
        Ol[(size_t)col * 256 + row] = f2bf(v - bf2f(hb));
      }
}

// ---------------- k_bnd: boundary states ----------------
// Y_c = T_c + T_{c-1}@M + T_{c-2}@M^2 + T_{c-3}@M^3, T_0=x0, T_k=S_{k-1}.
__global__ __launch_bounds__(512, 2) void k_bnd(const float* __restrict__ x0,
                                                const float* __restrict__ S,
                                                const uint16_t* __restrict__ M1h, const uint16_t* __restrict__ M1l,
                                                const uint16_t* __restrict__ M2h, const uint16_t* __restrict__ M2l,
                                                const uint16_t* __restrict__ M3h, const uint16_t* __restrict__ M3l,
                                                float* __restrict__ Y) {
  const int c = blockIdx.x;
  const int tid = threadIdx.x;
  const int w = tid >> 6, l = tid & 63, l15 = l & 15, quad = l >> 4;
  const int ns = w * 32;
  f32x4 acc[4][2];
  const float* Tc = (c == 0) ? x0 : (S + (size_t)(c - 1) * 64 * 256);
#pragma unroll
  for (int mf = 0; mf < 4; ++mf)
#pragma unroll
    for (int nf = 0; nf < 2; ++nf)
#pragma unroll
      for (int r = 0; r < 4; ++r)
        acc[mf][nf][r] = Tc[(size_t)(mf * 16 + quad * 4 + r) * 256 + ns + nf * 16 + l15];

  for (int j = 1; j <= 3; ++j) {
    int k = c - j;
    if (k < 0) break;
    const float* Tp = (k == 0) ? x0 : (S + (size_t)(k - 1) * 64 * 256);
    const uint16_t* Bh = (j == 1) ? M1h : (j == 2) ? M2h : M3h;
    const uint16_t* Bl = (j == 1) ? M1l : (j == 2) ? M2l : M3l;
#pragma unroll
    for (int mf = 0; mf < 4; ++mf) {
#pragma unroll
      for (int ks = 0; ks < 8; ++ks) {
        const float* ap = Tp + (size_t)(mf * 16 + l15) * 256 + ks * 32 + quad * 8;
        f32x4 f0 = *reinterpret_cast<const f32x4*>(ap);
        f32x4 f1 = *reinterpret_cast<const f32x4*>(ap + 4);
        float fv[8] = {f0[0], f0[1], f0[2], f0[3], f1[0], f1[1], f1[2], f1[3]};
        short8 ah, al8;
        split8(fv, ah, al8);
#pragma unroll
        for (int nf = 0; nf < 2; ++nf) {
          const int off = (ns + nf * 16 + l15) * 256 + ks * 32 + quad * 8;
          short8 bhf = *reinterpret_cast<const short8*>(Bh + off);
          short8 blf = *reinterpret_cast<const short8*>(Bl + off);
          acc[mf][nf] = MFMA16(ah, bhf, acc[mf][nf]);
          acc[mf][nf] = MFMA16(al8, bhf, acc[mf][nf]);
          acc[mf][nf] = MFMA16(ah, blf, acc[mf][nf]);
        }
      }
    }
  }
#pragma unroll
  for (int mf = 0; mf < 4; ++mf)
#pragma unroll
    for (int nf = 0; nf < 2; ++nf)
#pragma unroll
      for (int r = 0; r < 4; ++r)
        Y[(size_t)c * 64 * 256 + (size_t)(mf * 16 + quad * 4 + r) * 256 + ns + nf * 16 + l15] =
            acc[mf][nf][r];
}

// ---------------- launch ----------------
extern "C" void kernel_launch(void* const* d_in, const int* in_sizes, int n_in,
                              void* d_out, int out_size, void* d_ws, size_t ws_size,
                              hipStream_t stream) {
  (void)in_sizes; (void)n_in; (void)out_size; (void)ws_size;
  const float* x0 = (const float*)d_in[0];
  const float* I  = (const float*)d_in[1];
  const float* eW = (const float*)d_in[2];
  const float* Wi = (const float*)d_in[3];
  float* out = (float*)d_out;
  char* ws = (char*)d_ws;

  uint16_t* Ah  = (uint16_t*)(ws + WS_A_HI);
  uint16_t* Al  = (uint16_t*)(ws + WS_A_LO);
  uint16_t* Wh  = (uint16_t*)(ws + WS_WB_HI);
  uint16_t* Wl  = (uint16_t*)(ws + WS_WB_LO);
  float*    Mb  = (float*)(ws + WS_MBUF);
  uint16_t* Mh  = (uint16_t*)(ws + WS_M_HI);
  uint16_t* Ml  = (uint16_t*)(ws + WS_M_LO);
  float*    M2f = (float*)(ws + WS_M2F);
  uint16_t* M2h = (uint16_t*)(ws + WS_M2_HI);
  uint16_t* M2l = (uint16_t*)(ws + WS_M2_LO);
  float*    M3f = (float*)(ws + WS_M3F);
  uint16_t* M3h = (uint16_t*)(ws + WS_M3_HI);
  uint16_t* M3l = (uint16_t*)(ws + WS_M3_LO);
  float*    S   = (float*)(ws + WS_S);
  float*    Y   = (float*)(ws + WS_Y);

  k_split<<<512, 256, 0, stream>>>(eW, Wi, Ah, Al, Wh, Wl);
  k_u<<<1024, 512, 0, stream>>>(I, Wh, Wl, out);
  k_scan<<<144, 512, 0, stream>>>(1, Ah, Al, out, Y, S, Mb, Mh, Ml);
  k_mm256<<<1, 512, 0, stream>>>(Mb, Mh, Ml, M2f, M2h, M2l);   // M^2
  k_mm256<<<1, 512, 0, stream>>>(M2f, Mh, Ml, M3f, M3h, M3l);  // M^3
  k_bnd<<<32, 512, 0, stream>>>(x0, S, Mh, Ml, M2h, M2l, M3h, M3l, Y);
  k_scan<<<128, 512, 0, stream>>>(2, Ah, Al, out, Y, S, Mb, Mh, Ml);
}

// Round 2
// 410.864 us; speedup vs baseline: 1.4236x; 1.4236x over previous
//
#include <hip/hip_runtime.h>
#include <stdint.h>
#include <stddef.h>

// ISNNet: x[:,0]=x0; x[:,t] = x[:,t-1] @ eW.T + I[:,t-1] @ W_inv_eW.T
// B=64, T=2048, D=256.  3-term compensated bf16 MFMA throughout.
// Round 2: coop-split k_u, CHUNK=32 (depth-halved scans), parallel mm256, J=4.

#define BATCH 64
#define TLEN 2048
#define DDIM 256
#define CHUNK 32
#define NCHUNK 64

typedef __attribute__((ext_vector_type(8))) short short8;
typedef __attribute__((ext_vector_type(4))) float f32x4;

#define MFMA16(a, b, c) __builtin_amdgcn_mfma_f32_16x16x32_bf16((a), (b), (c), 0, 0, 0)

__device__ __forceinline__ uint16_t f2bf(float f) {
  union { float f; uint32_t u; } v; v.f = f;
  return (uint16_t)((v.u + 0x7fffu + ((v.u >> 16) & 1u)) >> 16);  // RNE
}
__device__ __forceinline__ float bf2f(uint16_t h) {
  union { uint32_t u; float f; } v; v.u = ((uint32_t)h) << 16;
  return v.f;
}

__device__ __forceinline__ void split8(const float* fv, short8& hi, short8& lo) {
#pragma unroll
  for (int j = 0; j < 8; ++j) {
    uint16_t hb = f2bf(fv[j]);
    hi[j] = (short)hb;
    lo[j] = (short)f2bf(fv[j] - bf2f(hb));
  }
}

// raw barrier: waits LDS ops but NOT outstanding global loads (keeps u-prefetch in flight)
__device__ __forceinline__ void wg_barrier() {
  __builtin_amdgcn_sched_barrier(0);
  asm volatile("s_waitcnt lgkmcnt(0)" ::: "memory");
  __builtin_amdgcn_s_barrier();
  asm volatile("" ::: "memory");
  __builtin_amdgcn_sched_barrier(0);
}

// ---------------- workspace layout (bytes) ----------------
#define WS_A_HI   (0)
#define WS_A_LO   (128 * 1024)
#define WS_WB_HI  (256 * 1024)
#define WS_WB_LO  (384 * 1024)
#define WS_M1F    (512 * 1024)   // f32 [256][256]
#define WS_M1_HI  (768 * 1024)
#define WS_M1_LO  (896 * 1024)
#define WS_M2F    (1024 * 1024)
#define WS_M2_HI  (1280 * 1024)
#define WS_M2_LO  (1408 * 1024)
#define WS_M3F    (1536 * 1024)
#define WS_M3_HI  (1792 * 1024)
#define WS_M3_LO  (1920 * 1024)
#define WS_M4F    (2048 * 1024)
#define WS_M4_HI  (2304 * 1024)
#define WS_M4_LO  (2432 * 1024)
#define WS_S      (2560 * 1024)  // f32 [64][64][256] = 4MB
#define WS_Y      (6656 * 1024)  // f32 [64][64][256] = 4MB
// total ~10.5MB

// ---------------- k_split ----------------
__global__ void k_split(const float* __restrict__ eW, const float* __restrict__ Wi,
                        uint16_t* __restrict__ Ah, uint16_t* __restrict__ Al,
                        uint16_t* __restrict__ Wh, uint16_t* __restrict__ Wl) {
  int idx = blockIdx.x * blockDim.x + threadIdx.x;
  if (idx < 65536) {
    float v = eW[idx];
    uint16_t h = f2bf(v);
    Ah[idx] = h;
    Al[idx] = f2bf(v - bf2f(h));
  } else if (idx < 131072) {
    int i = idx - 65536;
    float v = Wi[i];
    uint16_t h = f2bf(v);
    Wh[i] = h;
    Wl[i] = f2bf(v - bf2f(h));
  }
}

// ---------------- k_u: u = I @ Wb, stored into d_out at time t+1 ----------------
// Cooperative split: each I element split ONCE into LDS bf16 hi/lo planes.
__global__ __launch_bounds__(512, 2) void k_u(const float* __restrict__ I,
                                              const uint16_t* __restrict__ Wh,
                                              const uint16_t* __restrict__ Wl,
                                              float* __restrict__ out) {
  const int tid = threadIdx.x;
  const int w = tid >> 6, l = tid & 63, l15 = l & 15, quad = l >> 4;
  const int ns = w * 32;
  __shared__ __align__(16) uint16_t sIh[4096];  // 16 x 256 bf16, XOR-swizzled
  __shared__ __align__(16) uint16_t sIl[4096];

  // Wb column-slice fragments resident in regs (128 VGPR)
  short8 bh[2][8], bl[2][8];
#pragma unroll
  for (int nf = 0; nf < 2; ++nf)
#pragma unroll
    for (int ks = 0; ks < 8; ++ks) {
      const int off = (ns + nf * 16 + l15) * 256 + ks * 32 + quad * 8;
      bh[nf][ks] = *reinterpret_cast<const short8*>(Wh + off);
      bl[nf][ks] = *reinterpret_cast<const short8*>(Wl + off);
    }

  const int srow = tid >> 5;        // 0..15 (staging row)
  const int sc0 = (tid & 31) * 8;   // 0..248 (staging col base)
  const uint32_t wbyte =
      ((uint32_t)(srow * 512 + sc0 * 2)) ^ ((uint32_t)((srow & 7) << 4));

  for (int tl = blockIdx.x; tl < 8192; tl += 2048) {
    const int b = tl >> 7, tt = tl & 127;
    __syncthreads();  // protect LDS vs previous tile readers
    {
      const float* src = I + ((size_t)b * TLEN + tt * 16 + srow) * DDIM + sc0;
      f32x4 f0 = *reinterpret_cast<const f32x4*>(src);
      f32x4 f1 = *reinterpret_cast<const f32x4*>(src + 4);
      float fv[8] = {f0[0], f0[1], f0[2], f0[3], f1[0], f1[1], f1[2], f1[3]};
      short8 hi, lo;
      split8(fv, hi, lo);
      *reinterpret_cast<short8*>(reinterpret_cast<char*>(sIh) + wbyte) = hi;
      *reinterpret_cast<short8*>(reinterpret_cast<char*>(sIl) + wbyte) = lo;
    }
    __syncthreads();
    f32x4 acc0 = {0.f, 0.f, 0.f, 0.f}, acc1 = {0.f, 0.f, 0.f, 0.f};
#pragma unroll
    for (int ks = 0; ks < 8; ++ks) {
      uint32_t rb = (uint32_t)(l15 * 512 + ks * 64 + quad * 16) ^
                    (uint32_t)((l15 & 7) << 4);
      short8 ih = *reinterpret_cast<const short8*>((const char*)sIh + rb);
      short8 il = *reinterpret_cast<const short8*>((const char*)sIl + rb);
      acc0 = MFMA16(ih, bh[0][ks], acc0);
      acc0 = MFMA16(il, bh[0][ks], acc0);
      acc0 = MFMA16(ih, bl[0][ks], acc0);
      acc1 = MFMA16(ih, bh[1][ks], acc1);
      acc1 = MFMA16(il, bh[1][ks], acc1);
      acc1 = MFMA16(ih, bl[1][ks], acc1);
    }
#pragma unroll
    for (int nf = 0; nf < 2; ++nf)
#pragma unroll
      for (int r = 0; r < 4; ++r) {
        int trow = tt * 16 + quad * 4 + r;
        if (trow <= TLEN - 2) {  // u_t lives at location t+1; t <= 2046
          int col = ns + nf * 16 + l15;
          out[((size_t)b * TLEN + trow + 1) * DDIM + col] = (nf ? acc1 : acc0)[r];
        }
      }
  }
}

// ---------------- k_scan: in-chunk recurrence (CHUNK=32) ----------------
// pass 1: zero state -> S_c (+ 16 E-WGs propagate identity -> M = (eW^T)^32)
// pass 2: from Y_c -> write outputs
__global__ __launch_bounds__(512, 2) void k_scan(const int pass,
                                                 const uint16_t* __restrict__ Ah,
                                                 const uint16_t* __restrict__ Al,
                                                 float* __restrict__ xu,  // d_out: u in (shifted), x out
                                                 const float* __restrict__ Y,
                                                 float* __restrict__ S,
                                                 float* __restrict__ Mbuf,
                                                 uint16_t* __restrict__ Mh,
                                                 uint16_t* __restrict__ Ml) {
  const int tid = threadIdx.x;
  const int w = tid >> 6, l = tid & 63, l15 = l & 15, quad = l >> 4;
  const int ns = w * 32;
  bool isE = false;
  int c = 0, rg = 0, eb = 0;
  if (pass == 1 && blockIdx.x >= 256) {
    isE = true;
    eb = blockIdx.x - 256;
  } else {
    c = blockIdx.x >> 2;
    rg = blockIdx.x & 3;
  }
  __shared__ __align__(16) uint16_t sh[2][4096];
  __shared__ __align__(16) uint16_t sl[2][4096];

  // A fragments resident in registers (per-wave 32-col slice), 128 VGPR
  short8 fAh[2][8], fAl[2][8];
#pragma unroll
  for (int nf = 0; nf < 2; ++nf)
#pragma unroll
    for (int ks = 0; ks < 8; ++ks) {
      const int off = (ns + nf * 16 + l15) * 256 + ks * 32 + quad * 8;
      fAh[nf][ks] = *reinterpret_cast<const short8*>(Ah + off);
      fAl[nf][ks] = *reinterpret_cast<const short8*>(Al + off);
    }

  // init state (buf 0)
  for (int i = tid; i < 4096; i += 512) {
    int row = i >> 8, k = i & 255;
    float v;
    if (isE)
      v = (k == eb * 16 + row) ? 1.0f : 0.0f;
    else if (pass == 1)
      v = 0.0f;
    else {
      v = Y[((size_t)c * 64 + rg * 16 + row) * DDIM + k];
      if (c == 0) xu[((size_t)(rg * 16 + row) * TLEN) * DDIM + k] = v;  // x[:,0,:] = x0
    }
    uint16_t hb = f2bf(v);
    uint16_t lb = f2bf(v - bf2f(hb));
    uint32_t byte = (uint32_t)(row * 512 + k * 2) ^ (uint32_t)((row & 7) << 4);
    *(uint16_t*)((char*)sh[0] + byte) = hb;
    *(uint16_t*)((char*)sl[0] + byte) = lb;
  }
  __syncthreads();

  const int t0 = c * CHUNK;
  const int nsteps = isE ? CHUNK : ((t0 + CHUNK <= TLEN - 1) ? CHUNK : (TLEN - 1 - t0));

  float u0[8], u1[8], fin[8];
#pragma unroll
  for (int j = 0; j < 8; ++j) { u0[j] = 0.f; u1[j] = 0.f; fin[j] = 0.f; }

  auto issue_u = [&](int i, float (&dst)[8]) {
    if (isE || i > nsteps) return;
#pragma unroll
    for (int nf = 0; nf < 2; ++nf)
#pragma unroll
      for (int r = 0; r < 4; ++r) {
        int b = rg * 16 + quad * 4 + r;
        dst[nf * 4 + r] = xu[((size_t)b * TLEN + t0 + i) * DDIM + ns + nf * 16 + l15];
      }
  };
  issue_u(1, u0);
  issue_u(2, u1);

  int p = 0;
  auto step = [&](int i, float (&ucur)[8]) {
    f32x4 acc0 = {0.f, 0.f, 0.f, 0.f}, acc1 = {0.f, 0.f, 0.f, 0.f};
#pragma unroll
    for (int ks = 0; ks < 8; ++ks) {
      uint32_t byte = (uint32_t)(l15 * 512 + ks * 64 + quad * 16) ^ (uint32_t)((l15 & 7) << 4);
      short8 xh = *reinterpret_cast<const short8*>((const char*)sh[p] + byte);
      short8 xl = *reinterpret_cast<const short8*>((const char*)sl[p] + byte);
      acc0 = MFMA16(xh, fAh[0][ks], acc0);
      acc0 = MFMA16(xl, fAh[0][ks], acc0);
      acc0 = MFMA16(xh, fAl[0][ks], acc0);
      acc1 = MFMA16(xh, fAh[1][ks], acc1);
      acc1 = MFMA16(xl, fAh[1][ks], acc1);
      acc1 = MFMA16(xh, fAl[1][ks], acc1);
    }
#pragma unroll
    for (int nf = 0; nf < 2; ++nf)
#pragma unroll
      for (int r = 0; r < 4; ++r) {
        float v = (nf ? acc1 : acc0)[r];
        if (!isE) v += ucur[nf * 4 + r];
        fin[nf * 4 + r] = v;
      }
    if (pass == 2) {
#pragma unroll
      for (int nf = 0; nf < 2; ++nf)
#pragma unroll
        for (int r = 0; r < 4; ++r) {
          int b = rg * 16 + quad * 4 + r;
          xu[((size_t)b * TLEN + t0 + i) * DDIM + ns + nf * 16 + l15] = fin[nf * 4 + r];
        }
    }
    issue_u(i + 2, ucur);  // prefetch depth 2
    if (i < nsteps) {
#pragma unroll
      for (int nf = 0; nf < 2; ++nf)
#pragma unroll
        for (int r = 0; r < 4; ++r) {
          int row = quad * 4 + r, col = ns + nf * 16 + l15;
          float v = fin[nf * 4 + r];
          uint16_t hb = f2bf(v);
          uint16_t lb = f2bf(v - bf2f(hb));
          uint32_t byte = (uint32_t)(row * 512 + col * 2) ^ (uint32_t)((row & 7) << 4);
          *(uint16_t*)((char*)sh[p ^ 1] + byte) = hb;
          *(uint16_t*)((char*)sl[p ^ 1] + byte) = lb;
        }
      wg_barrier();
      p ^= 1;
    }
  };

  for (int i = 1; i + 1 <= nsteps; i += 2) {
    step(i, u0);
    step(i + 1, u1);
  }
  if (nsteps & 1) step(nsteps, u0);

  if (pass == 1) {
#pragma unroll
    for (int nf = 0; nf < 2; ++nf)
#pragma unroll
      for (int r = 0; r < 4; ++r) {
        int row = quad * 4 + r, col = ns + nf * 16 + l15;
        float v = fin[nf * 4 + r];
        if (isE) {
          int R = eb * 16 + row;
          Mbuf[(size_t)R * 256 + col] = v;
          uint16_t hb = f2bf(v);
          Mh[(size_t)col * 256 + R] = hb;
          Ml[(size_t)col * 256 + R] = f2bf(v - bf2f(hb));
        } else {
          S[((size_t)c * 64 + rg * 16 + row) * DDIM + col] = v;
        }
      }
  }
}

// ---------------- k_mm256: OUT = Af @ B, 16 WGs (one per 16-row slice) ----------------
__global__ __launch_bounds__(512, 2) void k_mm256(const float* __restrict__ Af,
                                                  const uint16_t* __restrict__ Bh,
                                                  const uint16_t* __restrict__ Bl,
                                                  float* __restrict__ Of,
                                                  uint16_t* __restrict__ Oh,
                                                  uint16_t* __restrict__ Ol) {
  const int mf = blockIdx.x;  // 0..15
  const int tid = threadIdx.x;
  const int w = tid >> 6, l = tid & 63, l15 = l & 15, quad = l >> 4;
  const int ns = w * 32;
  f32x4 acc[2];
  acc[0] = {0.f, 0.f, 0.f, 0.f};
  acc[1] = {0.f, 0.f, 0.f, 0.f};

#pragma unroll
  for (int ks = 0; ks < 8; ++ks) {
    const float* ap = Af + (size_t)(mf * 16 + l15) * 256 + ks * 32 + quad * 8;
    f32x4 f0 = *reinterpret_cast<const f32x4*>(ap);
    f32x4 f1 = *reinterpret_cast<const f32x4*>(ap + 4);
    float fv[8] = {f0[0], f0[1], f0[2], f0[3], f1[0], f1[1], f1[2], f1[3]};
    short8 ah, al8;
    split8(fv, ah, al8);
#pragma unroll
    for (int nf = 0; nf < 2; ++nf) {
      const int off = (ns + nf * 16 + l15) * 256 + ks * 32 + quad * 8;
      short8 bhf = *reinterpret_cast<const short8*>(Bh + off);
      short8 blf = *reinterpret_cast<const short8*>(Bl + off);
      acc[nf] = MFMA16(ah, bhf, acc[nf]);
      acc[nf] = MFMA16(al8, bhf, acc[nf]);
      acc[nf] = MFMA16(ah, blf, acc[nf]);
    }
  }
#pragma unroll
  for (int nf = 0; nf < 2; ++nf)
#pragma unroll
    for (int r = 0; r < 4; ++r) {
      int row = mf * 16 + quad * 4 + r;
      int col = ns + nf * 16 + l15;
      float v = acc[nf][r];
      Of[(size_t)row * 256 + col] = v;
      uint16_t hb = f2bf(v);
      Oh[(size_t)col * 256 + row] = hb;
      Ol[(size_t)col * 256 + row] = f2bf(v - bf2f(hb));
    }
}

// ---------------- k_bnd: boundary states, J=4 ----------------
// Y_c = T_c + T_{c-1}@M + T_{c-2}@M^2 + T_{c-3}@M^3 + T_{c-4}@M^4; T_0=x0, T_k=S_{k-1}.
__global__ __launch_bounds__(512, 2) void k_bnd(const float* __restrict__ x0,
                                                const float* __restrict__ S,
                                                const uint16_t* __restrict__ M1h, const uint16_t* __restrict__ M1l,
                                                const uint16_t* __restrict__ M2h, const uint16_t* __restrict__ M2l,
                                                const uint16_t* __restrict__ M3h, const uint16_t* __restrict__ M3l,
                                                const uint16_t* __restrict__ M4h, const uint16_t* __restrict__ M4l,
                                                float* __restrict__ Y) {
  const int c = blockIdx.x;
  const int tid = threadIdx.x;
  const int w = tid >> 6, l = tid & 63, l15 = l & 15, quad = l >> 4;
  const int ns = w * 32;
  f32x4 acc[4][2];
  const float* Tc = (c == 0) ? x0 : (S + (size_t)(c - 1) * 64 * 256);
#pragma unroll
  for (int mf = 0; mf < 4; ++mf)
#pragma unroll
    for (int nf = 0; nf < 2; ++nf)
#pragma unroll
      for (int r = 0; r < 4; ++r)
        acc[mf][nf][r] = Tc[(size_t)(mf * 16 + quad * 4 + r) * 256 + ns + nf * 16 + l15];

  for (int j = 1; j <= 4; ++j) {
    int k = c - j;
    if (k < 0) break;
    const float* Tp = (k == 0) ? x0 : (S + (size_t)(k - 1) * 64 * 256);
    const uint16_t* Bh = (j == 1) ? M1h : (j == 2) ? M2h : (j == 3) ? M3h : M4h;
    const uint16_t* Bl = (j == 1) ? M1l : (j == 2) ? M2l : (j == 3) ? M3l : M4l;
#pragma unroll
    for (int mf = 0; mf < 4; ++mf) {
#pragma unroll
      for (int ks = 0; ks < 8; ++ks) {
        const float* ap = Tp + (size_t)(mf * 16 + l15) * 256 + ks * 32 + quad * 8;
        f32x4 f0 = *reinterpret_cast<const f32x4*>(ap);
        f32x4 f1 = *reinterpret_cast<const f32x4*>(ap + 4);
        float fv[8] = {f0[0], f0[1], f0[2], f0[3], f1[0], f1[1], f1[2], f1[3]};
        short8 ah, al8;
        split8(fv, ah, al8);
#pragma unroll
        for (int nf = 0; nf < 2; ++nf) {
          const int off = (ns + nf * 16 + l15) * 256 + ks * 32 + quad * 8;
          short8 bhf = *reinterpret_cast<const short8*>(Bh + off);
          short8 blf = *reinterpret_cast<const short8*>(Bl + off);
          acc[mf][nf] = MFMA16(ah, bhf, acc[mf][nf]);
          acc[mf][nf] = MFMA16(al8, bhf, acc[mf][nf]);
          acc[mf][nf] = MFMA16(ah, blf, acc[mf][nf]);
        }
      }
    }
  }
#pragma unroll
  for (int mf = 0; mf < 4; ++mf)
#pragma unroll
    for (int nf = 0; nf < 2; ++nf)
#pragma unroll
      for (int r = 0; r < 4; ++r)
        Y[(size_t)c * 64 * 256 + (size_t)(mf * 16 + quad * 4 + r) * 256 + ns + nf * 16 + l15] =
            acc[mf][nf][r];
}

// ---------------- launch ----------------
extern "C" void kernel_launch(void* const* d_in, const int* in_sizes, int n_in,
                              void* d_out, int out_size, void* d_ws, size_t ws_size,
                              hipStream_t stream) {
  (void)in_sizes; (void)n_in; (void)out_size; (void)ws_size;
  const float* x0 = (const float*)d_in[0];
  const float* I  = (const float*)d_in[1];
  const float* eW = (const float*)d_in[2];
  const float* Wi = (const float*)d_in[3];
  float* out = (float*)d_out;
  char* ws = (char*)d_ws;

  uint16_t* Ah  = (uint16_t*)(ws + WS_A_HI);
  uint16_t* Al  = (uint16_t*)(ws + WS_A_LO);
  uint16_t* Wh  = (uint16_t*)(ws + WS_WB_HI);
  uint16_t* Wl  = (uint16_t*)(ws + WS_WB_LO);
  float*    M1f = (float*)(ws + WS_M1F);
  uint16_t* M1h = (uint16_t*)(ws + WS_M1_HI);
  uint16_t* M1l = (uint16_t*)(ws + WS_M1_LO);
  float*    M2f = (float*)(ws + WS_M2F);
  uint16_t* M2h = (uint16_t*)(ws + WS_M2_HI);
  uint16_t* M2l = (uint16_t*)(ws + WS_M2_LO);
  float*    M3f = (float*)(ws + WS_M3F);
  uint16_t* M3h = (uint16_t*)(ws + WS_M3_HI);
  uint16_t* M3l = (uint16_t*)(ws + WS_M3_LO);
  float*    M4f = (float*)(ws + WS_M4F);
  uint16_t* M4h = (uint16_t*)(ws + WS_M4_HI);
  uint16_t* M4l = (uint16_t*)(ws + WS_M4_LO);
  float*    S   = (float*)(ws + WS_S);
  float*    Y   = (float*)(ws + WS_Y);

  k_split<<<512, 256, 0, stream>>>(eW, Wi, Ah, Al, Wh, Wl);
  k_u<<<2048, 512, 0, stream>>>(I, Wh, Wl, out);
  k_scan<<<272, 512, 0, stream>>>(1, Ah, Al, out, Y, S, M1f, M1h, M1l);
  k_mm256<<<16, 512, 0, stream>>>(M1f, M1h, M1l, M2f, M2h, M2l);  // M^2
  k_mm256<<<16, 512, 0, stream>>>(M2f, M1h, M1l, M3f, M3h, M3l);  // M^3
  k_mm256<<<16, 512, 0, stream>>>(M3f, M1h, M1l, M4f, M4h, M4l);  // M^4
  k_bnd<<<64, 512, 0, stream>>>(x0, S, M1h, M1l, M2h, M2l, M3h, M3l, M4h, M4l, Y);
  k_scan<<<256, 512, 0, stream>>>(2, Ah, Al, out, Y, S, M1f, M1h, M1l);
}

// Round 3
// 380.581 us; speedup vs baseline: 1.5369x; 1.0796x over previous
//
#include <hip/hip_runtime.h>
#include <stdint.h>
#include <stddef.h>

// ISNNet: x[:,0]=x0; x[:,t] = x[:,t-1] @ eW.T + I[:,t-1] @ W_inv_eW.T
// B=64, T=2048, D=256.  3-term compensated bf16 MFMA throughout.
// Round 3: pinned register fragments (defeat remat), raw barriers (no vmcnt
// drain), k_u ping-pong prefetch, scan depth-4 u prefetch, 2-bit XOR swizzle.

#define BATCH 64
#define TLEN 2048
#define DDIM 256
#define CHUNK 32
#define NCHUNK 64

typedef __attribute__((ext_vector_type(8))) short short8;
typedef __attribute__((ext_vector_type(4))) float f32x4;

#define MFMA16(a, b, c) __builtin_amdgcn_mfma_f32_16x16x32_bf16((a), (b), (c), 0, 0, 0)
// Pin a short8 value into VGPRs: value becomes asm-defined -> compiler cannot
// rematerialize it from the original global load inside loops.
#define PIN8(x) asm volatile("" : "+v"(x))

__device__ __forceinline__ uint16_t f2bf(float f) {
  union { float f; uint32_t u; } v; v.f = f;
  return (uint16_t)((v.u + 0x7fffu + ((v.u >> 16) & 1u)) >> 16);  // RNE
}
__device__ __forceinline__ float bf2f(uint16_t h) {
  union { uint32_t u; float f; } v; v.u = ((uint32_t)h) << 16;
  return v.f;
}

__device__ __forceinline__ void split8(const float* fv, short8& hi, short8& lo) {
#pragma unroll
  for (int j = 0; j < 8; ++j) {
    uint16_t hb = f2bf(fv[j]);
    hi[j] = (short)hb;
    lo[j] = (short)f2bf(fv[j] - bf2f(hb));
  }
}

// rows 0..15 spread over 16 distinct 16B slots within 2 x 128B lines
__device__ __forceinline__ uint32_t swz(int row) {
  return ((uint32_t)((row & 7) << 4)) ^ ((uint32_t)(((row >> 3) & 1) << 7));
}

// raw barrier: waits LDS ops but NOT outstanding global loads
__device__ __forceinline__ void wg_barrier() {
  __builtin_amdgcn_sched_barrier(0);
  asm volatile("s_waitcnt lgkmcnt(0)" ::: "memory");
  __builtin_amdgcn_s_barrier();
  asm volatile("" ::: "memory");
  __builtin_amdgcn_sched_barrier(0);
}

// ---------------- workspace layout (bytes) ----------------
#define WS_A_HI   (0)
#define WS_A_LO   (128 * 1024)
#define WS_WB_HI  (256 * 1024)
#define WS_WB_LO  (384 * 1024)
#define WS_M1F    (512 * 1024)   // f32 [256][256]
#define WS_M1_HI  (768 * 1024)
#define WS_M1_LO  (896 * 1024)
#define WS_M2F    (1024 * 1024)
#define WS_M2_HI  (1280 * 1024)
#define WS_M2_LO  (1408 * 1024)
#define WS_M3F    (1536 * 1024)
#define WS_M3_HI  (1792 * 1024)
#define WS_M3_LO  (1920 * 1024)
#define WS_M4F    (2048 * 1024)
#define WS_M4_HI  (2304 * 1024)
#define WS_M4_LO  (2432 * 1024)
#define WS_S      (2560 * 1024)  // f32 [64][64][256] = 4MB
#define WS_Y      (6656 * 1024)  // f32 [64][64][256] = 4MB

// ---------------- k_split ----------------
__global__ void k_split(const float* __restrict__ eW, const float* __restrict__ Wi,
                        uint16_t* __restrict__ Ah, uint16_t* __restrict__ Al,
                        uint16_t* __restrict__ Wh, uint16_t* __restrict__ Wl) {
  int idx = blockIdx.x * blockDim.x + threadIdx.x;
  if (idx < 65536) {
    float v = eW[idx];
    uint16_t h = f2bf(v);
    Ah[idx] = h;
    Al[idx] = f2bf(v - bf2f(h));
  } else if (idx < 131072) {
    int i = idx - 65536;
    float v = Wi[i];
    uint16_t h = f2bf(v);
    Wh[i] = h;
    Wl[i] = f2bf(v - bf2f(h));
  }
}

// ---------------- k_u: u = I @ Wb, stored into d_out at time t+1 ----------------
__global__ __launch_bounds__(512, 2) void k_u(const float* __restrict__ I,
                                              const uint16_t* __restrict__ Wh,
                                              const uint16_t* __restrict__ Wl,
                                              float* __restrict__ out) {
  const int tid = threadIdx.x;
  const int w = tid >> 6, l = tid & 63, l15 = l & 15, quad = l >> 4;
  const int ns = w * 32;
  __shared__ __align__(16) uint16_t sIh[4096];  // 16 x 256 bf16, XOR-swizzled
  __shared__ __align__(16) uint16_t sIl[4096];

  // Wb column-slice fragments resident in regs (128 VGPR, pinned)
  short8 bh[2][8], bl[2][8];
#pragma unroll
  for (int nf = 0; nf < 2; ++nf)
#pragma unroll
    for (int ks = 0; ks < 8; ++ks) {
      const int off = (ns + nf * 16 + l15) * 256 + ks * 32 + quad * 8;
      bh[nf][ks] = *reinterpret_cast<const short8*>(Wh + off);
      bl[nf][ks] = *reinterpret_cast<const short8*>(Wl + off);
      PIN8(bh[nf][ks]);
      PIN8(bl[nf][ks]);
    }

  const int srow = tid >> 5;        // 0..15 (staging row)
  const int sc0 = (tid & 31) * 8;   // 0..248 (staging col base)
  const uint32_t wbyte = ((uint32_t)(srow * 512 + sc0 * 2)) ^ swz(srow);

  float ra[8], rb[8];
  auto loadI = [&](int tl, float (&dst)[8]) {
    const int b = tl >> 7, tt = tl & 127;
    const float* src = I + ((size_t)b * TLEN + tt * 16 + srow) * DDIM + sc0;
    *reinterpret_cast<f32x4*>(&dst[0]) = *reinterpret_cast<const f32x4*>(src);
    *reinterpret_cast<f32x4*>(&dst[4]) = *reinterpret_cast<const f32x4*>(src + 4);
  };

  auto do_tile = [&](int tl, float (&cur)[8], float (&nxt)[8], bool pre) {
    if (pre) loadI(tl + 1024, nxt);  // fire next tile's loads early
    short8 hi, lo;
    split8(cur, hi, lo);             // waits only cur's vmcnt
    wg_barrier();                    // prev compute's LDS reads done (no vmcnt drain)
    *reinterpret_cast<short8*>(reinterpret_cast<char*>(sIh) + wbyte) = hi;
    *reinterpret_cast<short8*>(reinterpret_cast<char*>(sIl) + wbyte) = lo;
    wg_barrier();
    const int b = tl >> 7, tt = tl & 127;
    f32x4 acc0 = {0.f, 0.f, 0.f, 0.f}, acc1 = {0.f, 0.f, 0.f, 0.f};
#pragma unroll
    for (int ks = 0; ks < 8; ++ks) {
      uint32_t rbyte = ((uint32_t)(l15 * 512 + ks * 64 + quad * 16)) ^ swz(l15);
      short8 ih = *reinterpret_cast<const short8*>((const char*)sIh + rbyte);
      short8 il = *reinterpret_cast<const short8*>((const char*)sIl + rbyte);
      acc0 = MFMA16(ih, bh[0][ks], acc0);
      acc0 = MFMA16(il, bh[0][ks], acc0);
      acc0 = MFMA16(ih, bl[0][ks], acc0);
      acc1 = MFMA16(ih, bh[1][ks], acc1);
      acc1 = MFMA16(il, bh[1][ks], acc1);
      acc1 = MFMA16(ih, bl[1][ks], acc1);
    }
#pragma unroll
    for (int nf = 0; nf < 2; ++nf)
#pragma unroll
      for (int r = 0; r < 4; ++r) {
        int trow = tt * 16 + quad * 4 + r;
        if (trow <= TLEN - 2) {  // u_t lives at location t+1; t <= 2046
          int col = ns + nf * 16 + l15;
          out[((size_t)b * TLEN + trow + 1) * DDIM + col] = (nf ? acc1 : acc0)[r];
        }
      }
  };

  const int tl0 = blockIdx.x;  // 8 tiles: tl0 + k*1024
  loadI(tl0, ra);
#pragma unroll
  for (int it = 0; it < 8; it += 2) {
    do_tile(tl0 + it * 1024, ra, rb, it + 1 < 8);
    do_tile(tl0 + (it + 1) * 1024, rb, ra, it + 2 < 8);
  }
}

// ---------------- k_scan: in-chunk recurrence (CHUNK=32) ----------------
__global__ __launch_bounds__(512, 2) void k_scan(const int pass,
                                                 const uint16_t* __restrict__ Ah,
                                                 const uint16_t* __restrict__ Al,
                                                 float* __restrict__ xu,  // d_out: u in (shifted), x out
                                                 const float* __restrict__ Y,
                                                 float* __restrict__ S,
                                                 float* __restrict__ Mbuf,
                                                 uint16_t* __restrict__ Mh,
                                                 uint16_t* __restrict__ Ml) {
  const int tid = threadIdx.x;
  const int w = tid >> 6, l = tid & 63, l15 = l & 15, quad = l >> 4;
  const int ns = w * 32;
  bool isE = false;
  int c = 0, rg = 0, eb = 0;
  if (pass == 1 && blockIdx.x >= 256) {
    isE = true;
    eb = blockIdx.x - 256;
  } else {
    c = blockIdx.x >> 2;
    rg = blockIdx.x & 3;
  }
  __shared__ __align__(16) uint16_t sh[2][4096];
  __shared__ __align__(16) uint16_t sl[2][4096];

  const int t0 = c * CHUNK;
  const int nsteps = isE ? CHUNK : ((t0 + CHUNK <= TLEN - 1) ? CHUNK : (TLEN - 1 - t0));

  float u0[8], u1[8], u2[8], u3[8], fin[8];
#pragma unroll
  for (int j = 0; j < 8; ++j) { u0[j] = 0.f; u1[j] = 0.f; u2[j] = 0.f; u3[j] = 0.f; fin[j] = 0.f; }

  auto issue_u = [&](int i, float (&dst)[8]) {
    if (isE || i > nsteps) return;
#pragma unroll
    for (int nf = 0; nf < 2; ++nf)
#pragma unroll
      for (int r = 0; r < 4; ++r) {
        int b = rg * 16 + quad * 4 + r;
        dst[nf * 4 + r] = xu[((size_t)b * TLEN + t0 + i) * DDIM + ns + nf * 16 + l15];
      }
  };
  // fire the first 4 steps' u loads before anything else
  issue_u(1, u0);
  issue_u(2, u1);
  issue_u(3, u2);
  issue_u(4, u3);

  // A fragments resident in registers (per-wave 32-col slice), pinned
  short8 fAh[2][8], fAl[2][8];
#pragma unroll
  for (int nf = 0; nf < 2; ++nf)
#pragma unroll
    for (int ks = 0; ks < 8; ++ks) {
      const int off = (ns + nf * 16 + l15) * 256 + ks * 32 + quad * 8;
      fAh[nf][ks] = *reinterpret_cast<const short8*>(Ah + off);
      fAl[nf][ks] = *reinterpret_cast<const short8*>(Al + off);
      PIN8(fAh[nf][ks]);
      PIN8(fAl[nf][ks]);
    }

  // init state (buf 0)
  for (int i = tid; i < 4096; i += 512) {
    int row = i >> 8, k = i & 255;
    float v;
    if (isE)
      v = (k == eb * 16 + row) ? 1.0f : 0.0f;
    else if (pass == 1)
      v = 0.0f;
    else {
      v = Y[((size_t)c * 64 + rg * 16 + row) * DDIM + k];
      if (c == 0) xu[((size_t)(rg * 16 + row) * TLEN) * DDIM + k] = v;  // x[:,0,:] = x0
    }
    uint16_t hb = f2bf(v);
    uint16_t lb = f2bf(v - bf2f(hb));
    uint32_t byte = ((uint32_t)(row * 512 + k * 2)) ^ swz(row);
    *(uint16_t*)((char*)sh[0] + byte) = hb;
    *(uint16_t*)((char*)sl[0] + byte) = lb;
  }
  wg_barrier();  // no vmcnt drain: u prefetches stay in flight

  int p = 0;
  auto step = [&](int i, float (&ucur)[8]) {
    f32x4 acc0 = {0.f, 0.f, 0.f, 0.f}, acc1 = {0.f, 0.f, 0.f, 0.f};
#pragma unroll
    for (int ks = 0; ks < 8; ++ks) {
      uint32_t byte = ((uint32_t)(l15 * 512 + ks * 64 + quad * 16)) ^ swz(l15);
      short8 xh = *reinterpret_cast<const short8*>((const char*)sh[p] + byte);
      short8 xl = *reinterpret_cast<const short8*>((const char*)sl[p] + byte);
      acc0 = MFMA16(xh, fAh[0][ks], acc0);
      acc0 = MFMA16(xl, fAh[0][ks], acc0);
      acc0 = MFMA16(xh, fAl[0][ks], acc0);
      acc1 = MFMA16(xh, fAh[1][ks], acc1);
      acc1 = MFMA16(xl, fAh[1][ks], acc1);
      acc1 = MFMA16(xh, fAl[1][ks], acc1);
    }
#pragma unroll
    for (int nf = 0; nf < 2; ++nf)
#pragma unroll
      for (int r = 0; r < 4; ++r) {
        float v = (nf ? acc1 : acc0)[r];
        if (!isE) v += ucur[nf * 4 + r];  // waits only ucur's loads (issued 4 steps ago)
        fin[nf * 4 + r] = v;
      }
    issue_u(i + 4, ucur);  // refill this buffer for step i+4
    if (pass == 2) {
#pragma unroll
      for (int nf = 0; nf < 2; ++nf)
#pragma unroll
        for (int r = 0; r < 4; ++r) {
          int b = rg * 16 + quad * 4 + r;
          xu[((size_t)b * TLEN + t0 + i) * DDIM + ns + nf * 16 + l15] = fin[nf * 4 + r];
        }
    }
    if (i < nsteps) {
#pragma unroll
      for (int nf = 0; nf < 2; ++nf)
#pragma unroll
        for (int r = 0; r < 4; ++r) {
          int row = quad * 4 + r, col = ns + nf * 16 + l15;
          float v = fin[nf * 4 + r];
          uint16_t hb = f2bf(v);
          uint16_t lb = f2bf(v - bf2f(hb));
          uint32_t byte = ((uint32_t)(row * 512 + col * 2)) ^ swz(row);
          *(uint16_t*)((char*)sh[p ^ 1] + byte) = hb;
          *(uint16_t*)((char*)sl[p ^ 1] + byte) = lb;
        }
      wg_barrier();
      p ^= 1;
    }
  };

  int i = 1;
  for (; i + 3 <= nsteps; i += 4) {
    step(i, u0);
    step(i + 1, u1);
    step(i + 2, u2);
    step(i + 3, u3);
  }
  if (i <= nsteps) { step(i, u0); ++i; }
  if (i <= nsteps) { step(i, u1); ++i; }
  if (i <= nsteps) { step(i, u2); ++i; }

  if (pass == 1) {
#pragma unroll
    for (int nf = 0; nf < 2; ++nf)
#pragma unroll
      for (int r = 0; r < 4; ++r) {
        int row = quad * 4 + r, col = ns + nf * 16 + l15;
        float v = fin[nf * 4 + r];
        if (isE) {
          int R = eb * 16 + row;
          Mbuf[(size_t)R * 256 + col] = v;
          uint16_t hb = f2bf(v);
          Mh[(size_t)col * 256 + R] = hb;
          Ml[(size_t)col * 256 + R] = f2bf(v - bf2f(hb));
        } else {
          S[((size_t)c * 64 + rg * 16 + row) * DDIM + col] = v;
        }
      }
  }
}

// ---------------- k_mm256: OUT = Af @ B, 16 WGs ----------------
__global__ __launch_bounds__(512, 2) void k_mm256(const float* __restrict__ Af,
                                                  const uint16_t* __restrict__ Bh,
                                                  const uint16_t* __restrict__ Bl,
                                                  float* __restrict__ Of,
                                                  uint16_t* __restrict__ Oh,
                                                  uint16_t* __restrict__ Ol) {
  const int mf = blockIdx.x;  // 0..15
  const int tid = threadIdx.x;
  const int w = tid >> 6, l = tid & 63, l15 = l & 15, quad = l >> 4;
  const int ns = w * 32;
  f32x4 acc[2];
  acc[0] = {0.f, 0.f, 0.f, 0.f};
  acc[1] = {0.f, 0.f, 0.f, 0.f};

#pragma unroll
  for (int ks = 0; ks < 8; ++ks) {
    const float* ap = Af + (size_t)(mf * 16 + l15) * 256 + ks * 32 + quad * 8;
    f32x4 f0 = *reinterpret_cast<const f32x4*>(ap);
    f32x4 f1 = *reinterpret_cast<const f32x4*>(ap + 4);
    float fv[8] = {f0[0], f0[1], f0[2], f0[3], f1[0], f1[1], f1[2], f1[3]};
    short8 ah, al8;
    split8(fv, ah, al8);
#pragma unroll
    for (int nf = 0; nf < 2; ++nf) {
      const int off = (ns + nf * 16 + l15) * 256 + ks * 32 + quad * 8;
      short8 bhf = *reinterpret_cast<const short8*>(Bh + off);
      short8 blf = *reinterpret_cast<const short8*>(Bl + off);
      acc[nf] = MFMA16(ah, bhf, acc[nf]);
      acc[nf] = MFMA16(al8, bhf, acc[nf]);
      acc[nf] = MFMA16(ah, blf, acc[nf]);
    }
  }
#pragma unroll
  for (int nf = 0; nf < 2; ++nf)
#pragma unroll
    for (int r = 0; r < 4; ++r) {
      int row = mf * 16 + quad * 4 + r;
      int col = ns + nf * 16 + l15;
      float v = acc[nf][r];
      Of[(size_t)row * 256 + col] = v;
      uint16_t hb = f2bf(v);
      Oh[(size_t)col * 256 + row] = hb;
      Ol[(size_t)col * 256 + row] = f2bf(v - bf2f(hb));
    }
}

// ---------------- k_bnd: boundary states, J=4 ----------------
__global__ __launch_bounds__(512, 2) void k_bnd(const float* __restrict__ x0,
                                                const float* __restrict__ S,
                                                const uint16_t* __restrict__ M1h, const uint16_t* __restrict__ M1l,
                                                const uint16_t* __restrict__ M2h, const uint16_t* __restrict__ M2l,
                                                const uint16_t* __restrict__ M3h, const uint16_t* __restrict__ M3l,
                                                const uint16_t* __restrict__ M4h, const uint16_t* __restrict__ M4l,
                                                float* __restrict__ Y) {
  const int c = blockIdx.x;
  const int tid = threadIdx.x;
  const int w = tid >> 6, l = tid & 63, l15 = l & 15, quad = l >> 4;
  const int ns = w * 32;
  f32x4 acc[4][2];
  const float* Tc = (c == 0) ? x0 : (S + (size_t)(c - 1) * 64 * 256);
#pragma unroll
  for (int mf = 0; mf < 4; ++mf)
#pragma unroll
    for (int nf = 0; nf < 2; ++nf)
#pragma unroll
      for (int r = 0; r < 4; ++r)
        acc[mf][nf][r] = Tc[(size_t)(mf * 16 + quad * 4 + r) * 256 + ns + nf * 16 + l15];

  for (int j = 1; j <= 4; ++j) {
    int k = c - j;
    if (k < 0) break;
    const float* Tp = (k == 0) ? x0 : (S + (size_t)(k - 1) * 64 * 256);
    const uint16_t* Bh = (j == 1) ? M1h : (j == 2) ? M2h : (j == 3) ? M3h : M4h;
    const uint16_t* Bl = (j == 1) ? M1l : (j == 2) ? M2l : (j == 3) ? M3l : M4l;
#pragma unroll
    for (int mf = 0; mf < 4; ++mf) {
#pragma unroll
      for (int ks = 0; ks < 8; ++ks) {
        const float* ap = Tp + (size_t)(mf * 16 + l15) * 256 + ks * 32 + quad * 8;
        f32x4 f0 = *reinterpret_cast<const f32x4*>(ap);
        f32x4 f1 = *reinterpret_cast<const f32x4*>(ap + 4);
        float fv[8] = {f0[0], f0[1], f0[2], f0[3], f1[0], f1[1], f1[2], f1[3]};
        short8 ah, al8;
        split8(fv, ah, al8);
#pragma unroll
        for (int nf = 0; nf < 2; ++nf) {
          const int off = (ns + nf * 16 + l15) * 256 + ks * 32 + quad * 8;
          short8 bhf = *reinterpret_cast<const short8*>(Bh + off);
          short8 blf = *reinterpret_cast<const short8*>(Bl + off);
          acc[mf][nf] = MFMA16(ah, bhf, acc[mf][nf]);
          acc[mf][nf] = MFMA16(al8, bhf, acc[mf][nf]);
          acc[mf][nf] = MFMA16(ah, blf, acc[mf][nf]);
        }
      }
    }
  }
#pragma unroll
  for (int mf = 0; mf < 4; ++mf)
#pragma unroll
    for (int nf = 0; nf < 2; ++nf)
#pragma unroll
      for (int r = 0; r < 4; ++r)
        Y[(size_t)c * 64 * 256 + (size_t)(mf * 16 + quad * 4 + r) * 256 + ns + nf * 16 + l15] =
            acc[mf][nf][r];
}

// ---------------- launch ----------------
extern "C" void kernel_launch(void* const* d_in, const int* in_sizes, int n_in,
                              void* d_out, int out_size, void* d_ws, size_t ws_size,
                              hipStream_t stream) {
  (void)in_sizes; (void)n_in; (void)out_size; (void)ws_size;
  const float* x0 = (const float*)d_in[0];
  const float* I  = (const float*)d_in[1];
  const float* eW = (const float*)d_in[2];
  const float* Wi = (const float*)d_in[3];
  float* out = (float*)d_out;
  char* ws = (char*)d_ws;

  uint16_t* Ah  = (uint16_t*)(ws + WS_A_HI);
  uint16_t* Al  = (uint16_t*)(ws + WS_A_LO);
  uint16_t* Wh  = (uint16_t*)(ws + WS_WB_HI);
  uint16_t* Wl  = (uint16_t*)(ws + WS_WB_LO);
  float*    M1f = (float*)(ws + WS_M1F);
  uint16_t* M1h = (uint16_t*)(ws + WS_M1_HI);
  uint16_t* M1l = (uint16_t*)(ws + WS_M1_LO);
  float*    M2f = (float*)(ws + WS_M2F);
  uint16_t* M2h = (uint16_t*)(ws + WS_M2_HI);
  uint16_t* M2l = (uint16_t*)(ws + WS_M2_LO);
  float*    M3f = (float*)(ws + WS_M3F);
  uint16_t* M3h = (uint16_t*)(ws + WS_M3_HI);
  uint16_t* M3l = (uint16_t*)(ws + WS_M3_LO);
  float*    M4f = (float*)(ws + WS_M4F);
  uint16_t* M4h = (uint16_t*)(ws + WS_M4_HI);
  uint16_t* M4l = (uint16_t*)(ws + WS_M4_LO);
  float*    S   = (float*)(ws + WS_S);
  float*    Y   = (float*)(ws + WS_Y);

  k_split<<<512, 256, 0, stream>>>(eW, Wi, Ah, Al, Wh, Wl);
  k_u<<<1024, 512, 0, stream>>>(I, Wh, Wl, out);
  k_scan<<<272, 512, 0, stream>>>(1, Ah, Al, out, Y, S, M1f, M1h, M1l);
  k_mm256<<<16, 512, 0, stream>>>(M1f, M1h, M1l, M2f, M2h, M2l);  // M^2
  k_mm256<<<16, 512, 0, stream>>>(M2f, M1h, M1l, M3f, M3h, M3l);  // M^3
  k_mm256<<<16, 512, 0, stream>>>(M3f, M1h, M1l, M4f, M4h, M4l);  // M^4
  k_bnd<<<64, 512, 0, stream>>>(x0, S, M1h, M1l, M2h, M2l, M3h, M3l, M4h, M4l, Y);
  k_scan<<<256, 512, 0, stream>>>(2, Ah, Al, out, Y, S, M1f, M1h, M1l);
}

// Round 4
// 359.519 us; speedup vs baseline: 1.6269x; 1.0586x over previous
//
#include <hip/hip_runtime.h>
#include <stdint.h>
#include <stddef.h>

// ISNNet: x[:,0]=x0; x[:,t] = x[:,t-1] @ eW.T + I[:,t-1] @ W_inv_eW.T
// B=64, T=2048, D=256.  3-term compensated bf16 MFMA throughout.
// Round 4: __launch_bounds__(512,1) -> VGPR cap 256 (was 128 -> pinned
// fragments spilled to scratch, reloaded every serial step). Persistent k_u.

#define BATCH 64
#define TLEN 2048
#define DDIM 256
#define CHUNK 32
#define NCHUNK 64

typedef __attribute__((ext_vector_type(8))) short short8;
typedef __attribute__((ext_vector_type(4))) float f32x4;

#define MFMA16(a, b, c) __builtin_amdgcn_mfma_f32_16x16x32_bf16((a), (b), (c), 0, 0, 0)
// Pin a short8 value into VGPRs: value becomes asm-defined -> compiler cannot
// rematerialize it from the original global load inside loops.
#define PIN8(x) asm volatile("" : "+v"(x))

__device__ __forceinline__ uint16_t f2bf(float f) {
  union { float f; uint32_t u; } v; v.f = f;
  return (uint16_t)((v.u + 0x7fffu + ((v.u >> 16) & 1u)) >> 16);  // RNE
}
__device__ __forceinline__ float bf2f(uint16_t h) {
  union { uint32_t u; float f; } v; v.u = ((uint32_t)h) << 16;
  return v.f;
}

__device__ __forceinline__ void split8(const float* fv, short8& hi, short8& lo) {
#pragma unroll
  for (int j = 0; j < 8; ++j) {
    uint16_t hb = f2bf(fv[j]);
    hi[j] = (short)hb;
    lo[j] = (short)f2bf(fv[j] - bf2f(hb));
  }
}

// rows 0..15 spread over 16 distinct 16B slots within 2 x 128B lines
__device__ __forceinline__ uint32_t swz(int row) {
  return ((uint32_t)((row & 7) << 4)) ^ ((uint32_t)(((row >> 3) & 1) << 7));
}

// raw barrier: waits LDS ops but NOT outstanding global loads
__device__ __forceinline__ void wg_barrier() {
  __builtin_amdgcn_sched_barrier(0);
  asm volatile("s_waitcnt lgkmcnt(0)" ::: "memory");
  __builtin_amdgcn_s_barrier();
  asm volatile("" ::: "memory");
  __builtin_amdgcn_sched_barrier(0);
}

// ---------------- workspace layout (bytes) ----------------
#define WS_A_HI   (0)
#define WS_A_LO   (128 * 1024)
#define WS_WB_HI  (256 * 1024)
#define WS_WB_LO  (384 * 1024)
#define WS_M1F    (512 * 1024)   // f32 [256][256]
#define WS_M1_HI  (768 * 1024)
#define WS_M1_LO  (896 * 1024)
#define WS_M2F    (1024 * 1024)
#define WS_M2_HI  (1280 * 1024)
#define WS_M2_LO  (1408 * 1024)
#define WS_M3F    (1536 * 1024)
#define WS_M3_HI  (1792 * 1024)
#define WS_M3_LO  (1920 * 1024)
#define WS_M4F    (2048 * 1024)
#define WS_M4_HI  (2304 * 1024)
#define WS_M4_LO  (2432 * 1024)
#define WS_S      (2560 * 1024)  // f32 [64][64][256] = 4MB
#define WS_Y      (6656 * 1024)  // f32 [64][64][256] = 4MB

// ---------------- k_split ----------------
__global__ void k_split(const float* __restrict__ eW, const float* __restrict__ Wi,
                        uint16_t* __restrict__ Ah, uint16_t* __restrict__ Al,
                        uint16_t* __restrict__ Wh, uint16_t* __restrict__ Wl) {
  int idx = blockIdx.x * blockDim.x + threadIdx.x;
  if (idx < 65536) {
    float v = eW[idx];
    uint16_t h = f2bf(v);
    Ah[idx] = h;
    Al[idx] = f2bf(v - bf2f(h));
  } else if (idx < 131072) {
    int i = idx - 65536;
    float v = Wi[i];
    uint16_t h = f2bf(v);
    Wh[i] = h;
    Wl[i] = f2bf(v - bf2f(h));
  }
}

// ---------------- k_u: u = I @ Wb, stored into d_out at time t+1 ----------------
// Persistent: 256 WGs x 32 tiles, Wb fragments loaded once, ping-pong prefetch.
__global__ __launch_bounds__(512, 1) void k_u(const float* __restrict__ I,
                                              const uint16_t* __restrict__ Wh,
                                              const uint16_t* __restrict__ Wl,
                                              float* __restrict__ out) {
  const int tid = threadIdx.x;
  const int w = tid >> 6, l = tid & 63, l15 = l & 15, quad = l >> 4;
  const int ns = w * 32;
  __shared__ __align__(16) uint16_t sIh[4096];  // 16 x 256 bf16, XOR-swizzled
  __shared__ __align__(16) uint16_t sIl[4096];

  // Wb column-slice fragments resident in regs (128 VGPR, pinned)
  short8 bh[2][8], bl[2][8];
#pragma unroll
  for (int nf = 0; nf < 2; ++nf)
#pragma unroll
    for (int ks = 0; ks < 8; ++ks) {
      const int off = (ns + nf * 16 + l15) * 256 + ks * 32 + quad * 8;
      bh[nf][ks] = *reinterpret_cast<const short8*>(Wh + off);
      bl[nf][ks] = *reinterpret_cast<const short8*>(Wl + off);
      PIN8(bh[nf][ks]);
      PIN8(bl[nf][ks]);
    }

  const int srow = tid >> 5;        // 0..15 (staging row)
  const int sc0 = (tid & 31) * 8;   // 0..248 (staging col base)
  const uint32_t wbyte = ((uint32_t)(srow * 512 + sc0 * 2)) ^ swz(srow);

  float ra[8], rb[8];
  auto loadI = [&](int tl, float (&dst)[8]) {
    const int b = tl >> 7, tt = tl & 127;
    const float* src = I + ((size_t)b * TLEN + tt * 16 + srow) * DDIM + sc0;
    *reinterpret_cast<f32x4*>(&dst[0]) = *reinterpret_cast<const f32x4*>(src);
    *reinterpret_cast<f32x4*>(&dst[4]) = *reinterpret_cast<const f32x4*>(src + 4);
  };

  auto do_tile = [&](int tl, float (&cur)[8], float (&nxt)[8], bool pre) {
    if (pre) loadI(tl + 256, nxt);  // fire next tile's loads early
    short8 hi, lo;
    split8(cur, hi, lo);             // waits only cur's vmcnt
    wg_barrier();                    // prev compute's LDS reads done (no vmcnt drain)
    *reinterpret_cast<short8*>(reinterpret_cast<char*>(sIh) + wbyte) = hi;
    *reinterpret_cast<short8*>(reinterpret_cast<char*>(sIl) + wbyte) = lo;
    wg_barrier();
    const int b = tl >> 7, tt = tl & 127;
    f32x4 acc0 = {0.f, 0.f, 0.f, 0.f}, acc1 = {0.f, 0.f, 0.f, 0.f};
#pragma unroll
    for (int ks = 0; ks < 8; ++ks) {
      uint32_t rbyte = ((uint32_t)(l15 * 512 + ks * 64 + quad * 16)) ^ swz(l15);
      short8 ih = *reinterpret_cast<const short8*>((const char*)sIh + rbyte);
      short8 il = *reinterpret_cast<const short8*>((const char*)sIl + rbyte);
      acc0 = MFMA16(ih, bh[0][ks], acc0);
      acc0 = MFMA16(il, bh[0][ks], acc0);
      acc0 = MFMA16(ih, bl[0][ks], acc0);
      acc1 = MFMA16(ih, bh[1][ks], acc1);
      acc1 = MFMA16(il, bh[1][ks], acc1);
      acc1 = MFMA16(ih, bl[1][ks], acc1);
    }
#pragma unroll
    for (int nf = 0; nf < 2; ++nf)
#pragma unroll
      for (int r = 0; r < 4; ++r) {
        int trow = tt * 16 + quad * 4 + r;
        if (trow <= TLEN - 2) {  // u_t lives at location t+1; t <= 2046
          int col = ns + nf * 16 + l15;
          out[((size_t)b * TLEN + trow + 1) * DDIM + col] = (nf ? acc1 : acc0)[r];
        }
      }
  };

  const int tl0 = blockIdx.x;  // 32 tiles: tl0 + k*256
  loadI(tl0, ra);
#pragma unroll 2
  for (int it = 0; it < 32; it += 2) {
    do_tile(tl0 + it * 256, ra, rb, it + 1 < 32);
    do_tile(tl0 + (it + 1) * 256, rb, ra, it + 2 < 32);
  }
}

// ---------------- k_scan: in-chunk recurrence (CHUNK=32) ----------------
__global__ __launch_bounds__(512, 1) void k_scan(const int pass,
                                                 const uint16_t* __restrict__ Ah,
                                                 const uint16_t* __restrict__ Al,
                                                 float* __restrict__ xu,  // d_out: u in (shifted), x out
                                                 const float* __restrict__ Y,
                                                 float* __restrict__ S,
                                                 float* __restrict__ Mbuf,
                                                 uint16_t* __restrict__ Mh,
                                                 uint16_t* __restrict__ Ml) {
  const int tid = threadIdx.x;
  const int w = tid >> 6, l = tid & 63, l15 = l & 15, quad = l >> 4;
  const int ns = w * 32;
  bool isE = false;
  int c = 0, rg = 0, eb = 0;
  if (pass == 1 && blockIdx.x >= 256) {
    isE = true;
    eb = blockIdx.x - 256;
  } else {
    c = blockIdx.x >> 2;
    rg = blockIdx.x & 3;
  }
  __shared__ __align__(16) uint16_t sh[2][4096];
  __shared__ __align__(16) uint16_t sl[2][4096];

  const int t0 = c * CHUNK;
  const int nsteps = isE ? CHUNK : ((t0 + CHUNK <= TLEN - 1) ? CHUNK : (TLEN - 1 - t0));

  float u0[8], u1[8], u2[8], u3[8], fin[8];
#pragma unroll
  for (int j = 0; j < 8; ++j) { u0[j] = 0.f; u1[j] = 0.f; u2[j] = 0.f; u3[j] = 0.f; fin[j] = 0.f; }

  auto issue_u = [&](int i, float (&dst)[8]) {
    if (isE || i > nsteps) return;
#pragma unroll
    for (int nf = 0; nf < 2; ++nf)
#pragma unroll
      for (int r = 0; r < 4; ++r) {
        int b = rg * 16 + quad * 4 + r;
        dst[nf * 4 + r] = xu[((size_t)b * TLEN + t0 + i) * DDIM + ns + nf * 16 + l15];
      }
  };
  // fire the first 4 steps' u loads before anything else
  issue_u(1, u0);
  issue_u(2, u1);
  issue_u(3, u2);
  issue_u(4, u3);

  // A fragments resident in registers (per-wave 32-col slice), pinned
  short8 fAh[2][8], fAl[2][8];
#pragma unroll
  for (int nf = 0; nf < 2; ++nf)
#pragma unroll
    for (int ks = 0; ks < 8; ++ks) {
      const int off = (ns + nf * 16 + l15) * 256 + ks * 32 + quad * 8;
      fAh[nf][ks] = *reinterpret_cast<const short8*>(Ah + off);
      fAl[nf][ks] = *reinterpret_cast<const short8*>(Al + off);
      PIN8(fAh[nf][ks]);
      PIN8(fAl[nf][ks]);
    }

  // init state (buf 0)
  for (int i = tid; i < 4096; i += 512) {
    int row = i >> 8, k = i & 255;
    float v;
    if (isE)
      v = (k == eb * 16 + row) ? 1.0f : 0.0f;
    else if (pass == 1)
      v = 0.0f;
    else {
      v = Y[((size_t)c * 64 + rg * 16 + row) * DDIM + k];
      if (c == 0) xu[((size_t)(rg * 16 + row) * TLEN) * DDIM + k] = v;  // x[:,0,:] = x0
    }
    uint16_t hb = f2bf(v);
    uint16_t lb = f2bf(v - bf2f(hb));
    uint32_t byte = ((uint32_t)(row * 512 + k * 2)) ^ swz(row);
    *(uint16_t*)((char*)sh[0] + byte) = hb;
    *(uint16_t*)((char*)sl[0] + byte) = lb;
  }
  wg_barrier();  // no vmcnt drain: u prefetches stay in flight

  int p = 0;
  auto step = [&](int i, float (&ucur)[8]) {
    f32x4 acc0 = {0.f, 0.f, 0.f, 0.f}, acc1 = {0.f, 0.f, 0.f, 0.f};
#pragma unroll
    for (int ks = 0; ks < 8; ++ks) {
      uint32_t byte = ((uint32_t)(l15 * 512 + ks * 64 + quad * 16)) ^ swz(l15);
      short8 xh = *reinterpret_cast<const short8*>((const char*)sh[p] + byte);
      short8 xl = *reinterpret_cast<const short8*>((const char*)sl[p] + byte);
      acc0 = MFMA16(xh, fAh[0][ks], acc0);
      acc0 = MFMA16(xl, fAh[0][ks], acc0);
      acc0 = MFMA16(xh, fAl[0][ks], acc0);
      acc1 = MFMA16(xh, fAh[1][ks], acc1);
      acc1 = MFMA16(xl, fAh[1][ks], acc1);
      acc1 = MFMA16(xh, fAl[1][ks], acc1);
    }
#pragma unroll
    for (int nf = 0; nf < 2; ++nf)
#pragma unroll
      for (int r = 0; r < 4; ++r) {
        float v = (nf ? acc1 : acc0)[r];
        if (!isE) v += ucur[nf * 4 + r];  // waits only ucur's loads (issued 4 steps ago)
        fin[nf * 4 + r] = v;
      }
    issue_u(i + 4, ucur);  // refill this buffer for step i+4
    if (pass == 2) {
#pragma unroll
      for (int nf = 0; nf < 2; ++nf)
#pragma unroll
        for (int r = 0; r < 4; ++r) {
          int b = rg * 16 + quad * 4 + r;
          xu[((size_t)b * TLEN + t0 + i) * DDIM + ns + nf * 16 + l15] = fin[nf * 4 + r];
        }
    }
    if (i < nsteps) {
#pragma unroll
      for (int nf = 0; nf < 2; ++nf)
#pragma unroll
        for (int r = 0; r < 4; ++r) {
          int row = quad * 4 + r, col = ns + nf * 16 + l15;
          float v = fin[nf * 4 + r];
          uint16_t hb = f2bf(v);
          uint16_t lb = f2bf(v - bf2f(hb));
          uint32_t byte = ((uint32_t)(row * 512 + col * 2)) ^ swz(row);
          *(uint16_t*)((char*)sh[p ^ 1] + byte) = hb;
          *(uint16_t*)((char*)sl[p ^ 1] + byte) = lb;
        }
      wg_barrier();
      p ^= 1;
    }
  };

  int i = 1;
  for (; i + 3 <= nsteps; i += 4) {
    step(i, u0);
    step(i + 1, u1);
    step(i + 2, u2);
    step(i + 3, u3);
  }
  if (i <= nsteps) { step(i, u0); ++i; }
  if (i <= nsteps) { step(i, u1); ++i; }
  if (i <= nsteps) { step(i, u2); ++i; }

  if (pass == 1) {
#pragma unroll
    for (int nf = 0; nf < 2; ++nf)
#pragma unroll
      for (int r = 0; r < 4; ++r) {
        int row = quad * 4 + r, col = ns + nf * 16 + l15;
        float v = fin[nf * 4 + r];
        if (isE) {
          int R = eb * 16 + row;
          Mbuf[(size_t)R * 256 + col] = v;
          uint16_t hb = f2bf(v);
          Mh[(size_t)col * 256 + R] = hb;
          Ml[(size_t)col * 256 + R] = f2bf(v - bf2f(hb));
        } else {
          S[((size_t)c * 64 + rg * 16 + row) * DDIM + col] = v;
        }
      }
  }
}

// ---------------- k_mm256: OUT = Af @ B, 16 WGs ----------------
__global__ __launch_bounds__(512, 1) void k_mm256(const float* __restrict__ Af,
                                                  const uint16_t* __restrict__ Bh,
                                                  const uint16_t* __restrict__ Bl,
                                                  float* __restrict__ Of,
                                                  uint16_t* __restrict__ Oh,
                                                  uint16_t* __restrict__ Ol) {
  const int mf = blockIdx.x;  // 0..15
  const int tid = threadIdx.x;
  const int w = tid >> 6, l = tid & 63, l15 = l & 15, quad = l >> 4;
  const int ns = w * 32;
  f32x4 acc[2];
  acc[0] = {0.f, 0.f, 0.f, 0.f};
  acc[1] = {0.f, 0.f, 0.f, 0.f};

#pragma unroll
  for (int ks = 0; ks < 8; ++ks) {
    const float* ap = Af + (size_t)(mf * 16 + l15) * 256 + ks * 32 + quad * 8;
    f32x4 f0 = *reinterpret_cast<const f32x4*>(ap);
    f32x4 f1 = *reinterpret_cast<const f32x4*>(ap + 4);
    float fv[8] = {f0[0], f0[1], f0[2], f0[3], f1[0], f1[1], f1[2], f1[3]};
    short8 ah, al8;
    split8(fv, ah, al8);
#pragma unroll
    for (int nf = 0; nf < 2; ++nf) {
      const int off = (ns + nf * 16 + l15) * 256 + ks * 32 + quad * 8;
      short8 bhf = *reinterpret_cast<const short8*>(Bh + off);
      short8 blf = *reinterpret_cast<const short8*>(Bl + off);
      acc[nf] = MFMA16(ah, bhf, acc[nf]);
      acc[nf] = MFMA16(al8, bhf, acc[nf]);
      acc[nf] = MFMA16(ah, blf, acc[nf]);
    }
  }
#pragma unroll
  for (int nf = 0; nf < 2; ++nf)
#pragma unroll
    for (int r = 0; r < 4; ++r) {
      int row = mf * 16 + quad * 4 + r;
      int col = ns + nf * 16 + l15;
      float v = acc[nf][r];
      Of[(size_t)row * 256 + col] = v;
      uint16_t hb = f2bf(v);
      Oh[(size_t)col * 256 + row] = hb;
      Ol[(size_t)col * 256 + row] = f2bf(v - bf2f(hb));
    }
}

// ---------------- k_bnd: boundary states, J=4 ----------------
__global__ __launch_bounds__(512, 1) void k_bnd(const float* __restrict__ x0,
                                                const float* __restrict__ S,
                                                const uint16_t* __restrict__ M1h, const uint16_t* __restrict__ M1l,
                                                const uint16_t* __restrict__ M2h, const uint16_t* __restrict__ M2l,
                                                const uint16_t* __restrict__ M3h, const uint16_t* __restrict__ M3l,
                                                const uint16_t* __restrict__ M4h, const uint16_t* __restrict__ M4l,
                                                float* __restrict__ Y) {
  const int c = blockIdx.x;
  const int tid = threadIdx.x;
  const int w = tid >> 6, l = tid & 63, l15 = l & 15, quad = l >> 4;
  const int ns = w * 32;
  f32x4 acc[4][2];
  const float* Tc = (c == 0) ? x0 : (S + (size_t)(c - 1) * 64 * 256);
#pragma unroll
  for (int mf = 0; mf < 4; ++mf)
#pragma unroll
    for (int nf = 0; nf < 2; ++nf)
#pragma unroll
      for (int r = 0; r < 4; ++r)
        acc[mf][nf][r] = Tc[(size_t)(mf * 16 + quad * 4 + r) * 256 + ns + nf * 16 + l15];

  for (int j = 1; j <= 4; ++j) {
    int k = c - j;
    if (k < 0) break;
    const float* Tp = (k == 0) ? x0 : (S + (size_t)(k - 1) * 64 * 256);
    const uint16_t* Bh = (j == 1) ? M1h : (j == 2) ? M2h : (j == 3) ? M3h : M4h;
    const uint16_t* Bl = (j == 1) ? M1l : (j == 2) ? M2l : (j == 3) ? M3l : M4l;
#pragma unroll
    for (int mf = 0; mf < 4; ++mf) {
#pragma unroll
      for (int ks = 0; ks < 8; ++ks) {
        const float* ap = Tp + (size_t)(mf * 16 + l15) * 256 + ks * 32 + quad * 8;
        f32x4 f0 = *reinterpret_cast<const f32x4*>(ap);
        f32x4 f1 = *reinterpret_cast<const f32x4*>(ap + 4);
        float fv[8] = {f0[0], f0[1], f0[2], f0[3], f1[0], f1[1], f1[2], f1[3]};
        short8 ah, al8;
        split8(fv, ah, al8);
#pragma unroll
        for (int nf = 0; nf < 2; ++nf) {
          const int off = (ns + nf * 16 + l15) * 256 + ks * 32 + quad * 8;
          short8 bhf = *reinterpret_cast<const short8*>(Bh + off);
          short8 blf = *reinterpret_cast<const short8*>(Bl + off);
          acc[mf][nf] = MFMA16(ah, bhf, acc[mf][nf]);
          acc[mf][nf] = MFMA16(al8, bhf, acc[mf][nf]);
          acc[mf][nf] = MFMA16(ah, blf, acc[mf][nf]);
        }
      }
    }
  }
#pragma unroll
  for (int mf = 0; mf < 4; ++mf)
#pragma unroll
    for (int nf = 0; nf < 2; ++nf)
#pragma unroll
      for (int r = 0; r < 4; ++r)
        Y[(size_t)c * 64 * 256 + (size_t)(mf * 16 + quad * 4 + r) * 256 + ns + nf * 16 + l15] =
            acc[mf][nf][r];
}

// ---------------- launch ----------------
extern "C" void kernel_launch(void* const* d_in, const int* in_sizes, int n_in,
                              void* d_out, int out_size, void* d_ws, size_t ws_size,
                              hipStream_t stream) {
  (void)in_sizes; (void)n_in; (void)out_size; (void)ws_size;
  const float* x0 = (const float*)d_in[0];
  const float* I  = (const float*)d_in[1];
  const float* eW = (const float*)d_in[2];
  const float* Wi = (const float*)d_in[3];
  float* out = (float*)d_out;
  char* ws = (char*)d_ws;

  uint16_t* Ah  = (uint16_t*)(ws + WS_A_HI);
  uint16_t* Al  = (uint16_t*)(ws + WS_A_LO);
  uint16_t* Wh  = (uint16_t*)(ws + WS_WB_HI);
  uint16_t* Wl  = (uint16_t*)(ws + WS_WB_LO);
  float*    M1f = (float*)(ws + WS_M1F);
  uint16_t* M1h = (uint16_t*)(ws + WS_M1_HI);
  uint16_t* M1l = (uint16_t*)(ws + WS_M1_LO);
  float*    M2f = (float*)(ws + WS_M2F);
  uint16_t* M2h = (uint16_t*)(ws + WS_M2_HI);
  uint16_t* M2l = (uint16_t*)(ws + WS_M2_LO);
  float*    M3f = (float*)(ws + WS_M3F);
  uint16_t* M3h = (uint16_t*)(ws + WS_M3_HI);
  uint16_t* M3l = (uint16_t*)(ws + WS_M3_LO);
  float*    M4f = (float*)(ws + WS_M4F);
  uint16_t* M4h = (uint16_t*)(ws + WS_M4_HI);
  uint16_t* M4l = (uint16_t*)(ws + WS_M4_LO);
  float*    S   = (float*)(ws + WS_S);
  float*    Y   = (float*)(ws + WS_Y);

  k_split<<<512, 256, 0, stream>>>(eW, Wi, Ah, Al, Wh, Wl);
  k_u<<<256, 512, 0, stream>>>(I, Wh, Wl, out);
  k_scan<<<272, 512, 0, stream>>>(1, Ah, Al, out, Y, S, M1f, M1h, M1l);
  k_mm256<<<16, 512, 0, stream>>>(M1f, M1h, M1l, M2f, M2h, M2l);  // M^2
  k_mm256<<<16, 512, 0, stream>>>(M2f, M1h, M1l, M3f, M3h, M3l);  // M^3
  k_mm256<<<16, 512, 0, stream>>>(M3f, M1h, M1l, M4f, M4h, M4l);  // M^4
  k_bnd<<<64, 512, 0, stream>>>(x0, S, M1h, M1l, M2h, M2l, M3h, M3l, M4h, M4l, Y);
  k_scan<<<256, 512, 0, stream>>>(2, Ah, Al, out, Y, S, M1f, M1h, M1l);
}

// Round 6
// 340.133 us; speedup vs baseline: 1.7196x; 1.0570x over previous
//
#include <hip/hip_runtime.h>
#include <stdint.h>
#include <stddef.h>

// ISNNet: x[:,0]=x0; x[:,t] = x[:,t-1] @ eW.T + I[:,t-1] @ W_inv_eW.T
// B=64, T=2048, D=256.  3-term compensated bf16 MFMA throughout.
// Round 6: revert nt-stores + waves_per_eu (post-timing nondeterminism in r5).
// k_scan -> 16-wave WGs (frags 64 VGPR/wave -> 4 waves/SIMD TLP).
// k_u -> LDS double-buffer (1 barrier/tile) + depth-4 register prefetch.

#define BATCH 64
#define TLEN 2048
#define DDIM 256
#define CHUNK 32
#define NCHUNK 64

typedef __attribute__((ext_vector_type(8))) short short8;
typedef __attribute__((ext_vector_type(4))) float f32x4;

#define MFMA16(a, b, c) __builtin_amdgcn_mfma_f32_16x16x32_bf16((a), (b), (c), 0, 0, 0)
#define PIN8(x) asm volatile("" : "+v"(x))

__device__ __forceinline__ uint16_t f2bf(float f) {
  union { float f; uint32_t u; } v; v.f = f;
  return (uint16_t)((v.u + 0x7fffu + ((v.u >> 16) & 1u)) >> 16);  // RNE
}
__device__ __forceinline__ float bf2f(uint16_t h) {
  union { uint32_t u; float f; } v; v.u = ((uint32_t)h) << 16;
  return v.f;
}

__device__ __forceinline__ void split8(const float* fv, short8& hi, short8& lo) {
#pragma unroll
  for (int j = 0; j < 8; ++j) {
    uint16_t hb = f2bf(fv[j]);
    hi[j] = (short)hb;
    lo[j] = (short)f2bf(fv[j] - bf2f(hb));
  }
}

// rows 0..15 spread over 16 distinct 16B slots within 2 x 128B lines
__device__ __forceinline__ uint32_t swz(int row) {
  return ((uint32_t)((row & 7) << 4)) ^ ((uint32_t)(((row >> 3) & 1) << 7));
}

// raw barrier: waits LDS ops but NOT outstanding global loads
__device__ __forceinline__ void wg_barrier() {
  __builtin_amdgcn_sched_barrier(0);
  asm volatile("s_waitcnt lgkmcnt(0)" ::: "memory");
  __builtin_amdgcn_s_barrier();
  asm volatile("" ::: "memory");
  __builtin_amdgcn_sched_barrier(0);
}

// ---------------- workspace layout (bytes) ----------------
#define WS_A_HI   (0)
#define WS_A_LO   (128 * 1024)
#define WS_WB_HI  (256 * 1024)
#define WS_WB_LO  (384 * 1024)
#define WS_M1F    (512 * 1024)   // f32 [256][256]
#define WS_M1_HI  (768 * 1024)
#define WS_M1_LO  (896 * 1024)
#define WS_M2F    (1024 * 1024)
#define WS_M2_HI  (1280 * 1024)
#define WS_M2_LO  (1408 * 1024)
#define WS_M3F    (1536 * 1024)
#define WS_M3_HI  (1792 * 1024)
#define WS_M3_LO  (1920 * 1024)
#define WS_ATF    (2048 * 1024)  // f32 eW^T (A1 row-major), 256KB
#define WS_S      (2560 * 1024)  // f32 [64][64][256] = 4MB
#define WS_Y      (6656 * 1024)  // f32 [64][64][256] = 4MB

// ---------------- k_split ----------------
__global__ void k_split(const float* __restrict__ eW, const float* __restrict__ Wi,
                        uint16_t* __restrict__ Ah, uint16_t* __restrict__ Al,
                        uint16_t* __restrict__ Wh, uint16_t* __restrict__ Wl,
                        float* __restrict__ AtF) {
  int idx = blockIdx.x * blockDim.x + threadIdx.x;
  if (idx < 65536) {
    float v = eW[idx];
    uint16_t h = f2bf(v);
    Ah[idx] = h;
    Al[idx] = f2bf(v - bf2f(h));
    AtF[(idx & 255) * 256 + (idx >> 8)] = v;  // AtF[k][n] = eW[n][k]
  } else if (idx < 131072) {
    int i = idx - 65536;
    float v = Wi[i];
    uint16_t h = f2bf(v);
    Wh[i] = h;
    Wl[i] = f2bf(v - bf2f(h));
  }
}

// ---------------- k_u: u = I @ Wb, stored into d_out at time t+1 ----------------
// Persistent 256 WGs x 32 tiles; LDS double-buffer (1 barrier/tile); depth-4
// register prefetch (distance 2 tiles).
__global__ __launch_bounds__(512, 1) void k_u(const float* __restrict__ I,
                                              const uint16_t* __restrict__ Wh,
                                              const uint16_t* __restrict__ Wl,
                                              float* __restrict__ out) {
  const int tid = threadIdx.x;
  const int w = tid >> 6, l = tid & 63, l15 = l & 15, quad = l >> 4;
  const int ns = w * 32;
  __shared__ __align__(16) uint16_t sIh[2][4096];  // 16 x 256 bf16, XOR-swizzled
  __shared__ __align__(16) uint16_t sIl[2][4096];

  // Wb column-slice fragments resident (pinned; land in ACC VGPRs)
  short8 bh[2][8], bl[2][8];
#pragma unroll
  for (int nf = 0; nf < 2; ++nf)
#pragma unroll
    for (int ks = 0; ks < 8; ++ks) {
      const int off = (ns + nf * 16 + l15) * 256 + ks * 32 + quad * 8;
      bh[nf][ks] = *reinterpret_cast<const short8*>(Wh + off);
      bl[nf][ks] = *reinterpret_cast<const short8*>(Wl + off);
      PIN8(bh[nf][ks]);
      PIN8(bl[nf][ks]);
    }

  const int srow = tid >> 5;        // 0..15 (staging row)
  const int sc0 = (tid & 31) * 8;   // 0..248 (staging col base)
  const uint32_t wbyte = ((uint32_t)(srow * 512 + sc0 * 2)) ^ swz(srow);

  float ra[8], rb[8], rc[8], rd[8];
  auto loadI = [&](int tl, float (&dst)[8]) {
    const int b = tl >> 7, tt = tl & 127;
    const float* src = I + ((size_t)b * TLEN + tt * 16 + srow) * DDIM + sc0;
    *reinterpret_cast<f32x4*>(&dst[0]) = *reinterpret_cast<const f32x4*>(src);
    *reinterpret_cast<f32x4*>(&dst[4]) = *reinterpret_cast<const f32x4*>(src + 4);
  };

  auto do_tile = [&](int tl, float (&cur)[8], float (&pf)[8], int q, bool pre) {
    if (pre) loadI(tl + 512, pf);    // prefetch tile tl+2 (stride 256)
    short8 hi, lo;
    split8(cur, hi, lo);             // waits only cur's vmcnt
    *reinterpret_cast<short8*>(reinterpret_cast<char*>(sIh[q]) + wbyte) = hi;
    *reinterpret_cast<short8*>(reinterpret_cast<char*>(sIl[q]) + wbyte) = lo;
    wg_barrier();                    // writes of buf q visible; buf q^1 free
    const int b = tl >> 7, tt = tl & 127;
    f32x4 acc0 = {0.f, 0.f, 0.f, 0.f}, acc1 = {0.f, 0.f, 0.f, 0.f};
#pragma unroll
    for (int ks = 0; ks < 8; ++ks) {
      uint32_t rbyte = ((uint32_t)(l15 * 512 + ks * 64 + quad * 16)) ^ swz(l15);
      short8 ih = *reinterpret_cast<const short8*>((const char*)sIh[q] + rbyte);
      short8 il = *reinterpret_cast<const short8*>((const char*)sIl[q] + rbyte);
      acc0 = MFMA16(ih, bh[0][ks], acc0);
      acc0 = MFMA16(il, bh[0][ks], acc0);
      acc0 = MFMA16(ih, bl[0][ks], acc0);
      acc1 = MFMA16(ih, bh[1][ks], acc1);
      acc1 = MFMA16(il, bh[1][ks], acc1);
      acc1 = MFMA16(ih, bl[1][ks], acc1);
    }
#pragma unroll
    for (int nf = 0; nf < 2; ++nf)
#pragma unroll
      for (int r = 0; r < 4; ++r) {
        int trow = tt * 16 + quad * 4 + r;
        if (trow <= TLEN - 2) {  // u_t lives at location t+1; t <= 2046
          int col = ns + nf * 16 + l15;
          out[((size_t)b * TLEN + trow + 1) * DDIM + col] = (nf ? acc1 : acc0)[r];
        }
      }
  };

  const int tl0 = blockIdx.x;  // 32 tiles: tl0 + k*256
  loadI(tl0, ra);
  loadI(tl0 + 256, rb);
#pragma unroll 1
  for (int it = 0; it < 32; it += 4) {
    do_tile(tl0 + (it + 0) * 256, ra, rc, 0, it + 2 < 32);
    do_tile(tl0 + (it + 1) * 256, rb, rd, 1, it + 3 < 32);
    do_tile(tl0 + (it + 2) * 256, rc, ra, 0, it + 4 < 32);
    do_tile(tl0 + (it + 3) * 256, rd, rb, 1, it + 5 < 32);
  }
}

// ---------------- k_scan: in-chunk recurrence (CHUNK=32), 16-wave WGs ----------------
// grid 256: c = blockIdx>>2, rg = blockIdx&3. Each wave owns 16 N-cols ->
// fragments 64 VGPR/wave -> 4 waves/SIMD.
__global__ __launch_bounds__(1024) void k_scan(const int pass,
                                               const uint16_t* __restrict__ Ah,
                                               const uint16_t* __restrict__ Al,
                                               float* __restrict__ xu,  // d_out: u in (shifted), x out
                                               const float* __restrict__ Y,
                                               float* __restrict__ S) {
  const int tid = threadIdx.x;
  const int w = tid >> 6, l = tid & 63, l15 = l & 15, quad = l >> 4;
  const int ns = w * 16;  // 16 cols per wave
  const int c = blockIdx.x >> 2;
  const int rg = blockIdx.x & 3;
  __shared__ __align__(16) uint16_t sh[2][4096];
  __shared__ __align__(16) uint16_t sl[2][4096];

  const int t0 = c * CHUNK;
  const int nsteps = (t0 + CHUNK <= TLEN - 1) ? CHUNK : (TLEN - 1 - t0);

  float u0[4], u1[4], u2[4], u3[4], fin[4];
#pragma unroll
  for (int j = 0; j < 4; ++j) { u0[j] = 0.f; u1[j] = 0.f; u2[j] = 0.f; u3[j] = 0.f; fin[j] = 0.f; }

  auto issue_u = [&](int i, float (&dst)[4]) {
    if (i > nsteps) return;
#pragma unroll
    for (int r = 0; r < 4; ++r) {
      int b = rg * 16 + quad * 4 + r;
      dst[r] = xu[((size_t)b * TLEN + t0 + i) * DDIM + ns + l15];
    }
  };
  issue_u(1, u0);
  issue_u(2, u1);
  issue_u(3, u2);
  issue_u(4, u3);

  // A fragments: per-wave 16-col slice (64 VGPR, pinned)
  short8 fAh[8], fAl[8];
#pragma unroll
  for (int ks = 0; ks < 8; ++ks) {
    const int off = (ns + l15) * 256 + ks * 32 + quad * 8;
    fAh[ks] = *reinterpret_cast<const short8*>(Ah + off);
    fAl[ks] = *reinterpret_cast<const short8*>(Al + off);
    PIN8(fAh[ks]);
    PIN8(fAl[ks]);
  }

  // init state (buf 0)
  for (int i = tid; i < 4096; i += 1024) {
    int row = i >> 8, k = i & 255;
    float v;
    if (pass == 1)
      v = 0.0f;
    else {
      v = Y[((size_t)c * 64 + rg * 16 + row) * DDIM + k];
      if (c == 0) xu[((size_t)(rg * 16 + row) * TLEN) * DDIM + k] = v;  // x[:,0,:] = x0
    }
    uint16_t hb = f2bf(v);
    uint16_t lb = f2bf(v - bf2f(hb));
    uint32_t byte = ((uint32_t)(row * 512 + k * 2)) ^ swz(row);
    *(uint16_t*)((char*)sh[0] + byte) = hb;
    *(uint16_t*)((char*)sl[0] + byte) = lb;
  }
  wg_barrier();  // no vmcnt drain: u prefetches stay in flight

  int p = 0;
  auto step = [&](int i, float (&ucur)[4]) {
    f32x4 acc = {0.f, 0.f, 0.f, 0.f};
#pragma unroll
    for (int ks = 0; ks < 8; ++ks) {
      uint32_t byte = ((uint32_t)(l15 * 512 + ks * 64 + quad * 16)) ^ swz(l15);
      short8 xh = *reinterpret_cast<const short8*>((const char*)sh[p] + byte);
      short8 xl = *reinterpret_cast<const short8*>((const char*)sl[p] + byte);
      acc = MFMA16(xh, fAh[ks], acc);
      acc = MFMA16(xl, fAh[ks], acc);
      acc = MFMA16(xh, fAl[ks], acc);
    }
#pragma unroll
    for (int r = 0; r < 4; ++r) fin[r] = acc[r] + ucur[r];
    issue_u(i + 4, ucur);  // refill this buffer for step i+4
    if (pass == 2) {
#pragma unroll
      for (int r = 0; r < 4; ++r) {
        int b = rg * 16 + quad * 4 + r;
        xu[((size_t)b * TLEN + t0 + i) * DDIM + ns + l15] = fin[r];
      }
    }
    if (i < nsteps) {
#pragma unroll
      for (int r = 0; r < 4; ++r) {
        int row = quad * 4 + r, col = ns + l15;
        float v = fin[r];
        uint16_t hb = f2bf(v);
        uint16_t lb = f2bf(v - bf2f(hb));
        uint32_t byte = ((uint32_t)(row * 512 + col * 2)) ^ swz(row);
        *(uint16_t*)((char*)sh[p ^ 1] + byte) = hb;
        *(uint16_t*)((char*)sl[p ^ 1] + byte) = lb;
      }
      wg_barrier();
      p ^= 1;
    }
  };

  int i = 1;
  for (; i + 3 <= nsteps; i += 4) {
    step(i, u0);
    step(i + 1, u1);
    step(i + 2, u2);
    step(i + 3, u3);
  }
  if (i <= nsteps) { step(i, u0); ++i; }
  if (i <= nsteps) { step(i, u1); ++i; }
  if (i <= nsteps) { step(i, u2); ++i; }

  if (pass == 1) {
#pragma unroll
    for (int r = 0; r < 4; ++r) {
      int row = quad * 4 + r, col = ns + l15;
      S[((size_t)c * 64 + rg * 16 + row) * DDIM + col] = fin[r];
    }
  }
}

// ---------------- k_mm256: OUT = Af @ B, 16 WGs ----------------
__global__ __launch_bounds__(512) void k_mm256(const float* __restrict__ Af,
                                               const uint16_t* __restrict__ Bh,
                                               const uint16_t* __restrict__ Bl,
                                               float* __restrict__ Of,
                                               uint16_t* __restrict__ Oh,
                                               uint16_t* __restrict__ Ol) {
  const int mf = blockIdx.x;  // 0..15
  const int tid = threadIdx.x;
  const int w = tid >> 6, l = tid & 63, l15 = l & 15, quad = l >> 4;
  const int ns = w * 32;
  f32x4 acc[2];
  acc[0] = {0.f, 0.f, 0.f, 0.f};
  acc[1] = {0.f, 0.f, 0.f, 0.f};

#pragma unroll
  for (int ks = 0; ks < 8; ++ks) {
    const float* ap = Af + (size_t)(mf * 16 + l15) * 256 + ks * 32 + quad * 8;
    f32x4 f0 = *reinterpret_cast<const f32x4*>(ap);
    f32x4 f1 = *reinterpret_cast<const f32x4*>(ap + 4);
    float fv[8] = {f0[0], f0[1], f0[2], f0[3], f1[0], f1[1], f1[2], f1[3]};
    short8 ah, al8;
    split8(fv, ah, al8);
#pragma unroll
    for (int nf = 0; nf < 2; ++nf) {
      const int off = (ns + nf * 16 + l15) * 256 + ks * 32 + quad * 8;
      short8 bhf = *reinterpret_cast<const short8*>(Bh + off);
      short8 blf = *reinterpret_cast<const short8*>(Bl + off);
      acc[nf] = MFMA16(ah, bhf, acc[nf]);
      acc[nf] = MFMA16(al8, bhf, acc[nf]);
      acc[nf] = MFMA16(ah, blf, acc[nf]);
    }
  }
#pragma unroll
  for (int nf = 0; nf < 2; ++nf)
#pragma unroll
    for (int r = 0; r < 4; ++r) {
      int row = mf * 16 + quad * 4 + r;
      int col = ns + nf * 16 + l15;
      float v = acc[nf][r];
      Of[(size_t)row * 256 + col] = v;
      uint16_t hb = f2bf(v);
      Oh[(size_t)col * 256 + row] = hb;
      Ol[(size_t)col * 256 + row] = f2bf(v - bf2f(hb));
    }
}

// ---------------- k_bnd: boundary states, J=3 ----------------
// Y_c = T_c + T_{c-1}@M1 + T_{c-2}@M2 + T_{c-3}@M3; T_0=x0, T_k=S_{k-1}.
__global__ __launch_bounds__(512) void k_bnd(const float* __restrict__ x0,
                                             const float* __restrict__ S,
                                             const uint16_t* __restrict__ M1h, const uint16_t* __restrict__ M1l,
                                             const uint16_t* __restrict__ M2h, const uint16_t* __restrict__ M2l,
                                             const uint16_t* __restrict__ M3h, const uint16_t* __restrict__ M3l,
                                             float* __restrict__ Y) {
  const int c = blockIdx.x;
  const int tid = threadIdx.x;
  const int w = tid >> 6, l = tid & 63, l15 = l & 15, quad = l >> 4;
  const int ns = w * 32;
  f32x4 acc[4][2];
  const float* Tc = (c == 0) ? x0 : (S + (size_t)(c - 1) * 64 * 256);
#pragma unroll
  for (int mf = 0; mf < 4; ++mf)
#pragma unroll
    for (int nf = 0; nf < 2; ++nf)
#pragma unroll
      for (int r = 0; r < 4; ++r)
        acc[mf][nf][r] = Tc[(size_t)(mf * 16 + quad * 4 + r) * 256 + ns + nf * 16 + l15];

  for (int j = 1; j <= 3; ++j) {
    int k = c - j;
    if (k < 0) break;
    const float* Tp = (k == 0) ? x0 : (S + (size_t)(k - 1) * 64 * 256);
    const uint16_t* Bh = (j == 1) ? M1h : (j == 2) ? M2h : M3h;
    const uint16_t* Bl = (j == 1) ? M1l : (j == 2) ? M2l : M3l;
#pragma unroll
    for (int mf = 0; mf < 4; ++mf) {
#pragma unroll
      for (int ks = 0; ks < 8; ++ks) {
        const float* ap = Tp + (size_t)(mf * 16 + l15) * 256 + ks * 32 + quad * 8;
        f32x4 f0 = *reinterpret_cast<const f32x4*>(ap);
        f32x4 f1 = *reinterpret_cast<const f32x4*>(ap + 4);
        float fv[8] = {f0[0], f0[1], f0[2], f0[3], f1[0], f1[1], f1[2], f1[3]};
        short8 ah, al8;
        split8(fv, ah, al8);
#pragma unroll
        for (int nf = 0; nf < 2; ++nf) {
          const int off = (ns + nf * 16 + l15) * 256 + ks * 32 + quad * 8;
          short8 bhf = *reinterpret_cast<const short8*>(Bh + off);
          short8 blf = *reinterpret_cast<const short8*>(Bl + off);
          acc[mf][nf] = MFMA16(ah, bhf, acc[mf][nf]);
          acc[mf][nf] = MFMA16(al8, bhf, acc[mf][nf]);
          acc[mf][nf] = MFMA16(ah, blf, acc[mf][nf]);
        }
      }
    }
  }
#pragma unroll
  for (int mf = 0; mf < 4; ++mf)
#pragma unroll
    for (int nf = 0; nf < 2; ++nf)
#pragma unroll
      for (int r = 0; r < 4; ++r)
        Y[(size_t)c * 64 * 256 + (size_t)(mf * 16 + quad * 4 + r) * 256 + ns + nf * 16 + l15] =
            acc[mf][nf][r];
}

// ---------------- launch ----------------
extern "C" void kernel_launch(void* const* d_in, const int* in_sizes, int n_in,
                              void* d_out, int out_size, void* d_ws, size_t ws_size,
                              hipStream_t stream) {
  (void)in_sizes; (void)n_in; (void)out_size; (void)ws_size;
  const float* x0 = (const float*)d_in[0];
  const float* I  = (const float*)d_in[1];
  const float* eW = (const float*)d_in[2];
  const float* Wi = (const float*)d_in[3];
  float* out = (float*)d_out;
  char* ws = (char*)d_ws;

  uint16_t* Ah  = (uint16_t*)(ws + WS_A_HI);
  uint16_t* Al  = (uint16_t*)(ws + WS_A_LO);
  uint16_t* Wh  = (uint16_t*)(ws + WS_WB_HI);
  uint16_t* Wl  = (uint16_t*)(ws + WS_WB_LO);
  float*    M1f = (float*)(ws + WS_M1F);
  uint16_t* M1h = (uint16_t*)(ws + WS_M1_HI);
  uint16_t* M1l = (uint16_t*)(ws + WS_M1_LO);
  float*    M2f = (float*)(ws + WS_M2F);
  uint16_t* M2h = (uint16_t*)(ws + WS_M2_HI);
  uint16_t* M2l = (uint16_t*)(ws + WS_M2_LO);
  float*    M3f = (float*)(ws + WS_M3F);
  uint16_t* M3h = (uint16_t*)(ws + WS_M3_HI);
  uint16_t* M3l = (uint16_t*)(ws + WS_M3_LO);
  float*    AtF = (float*)(ws + WS_ATF);
  float*    S   = (float*)(ws + WS_S);
  float*    Y   = (float*)(ws + WS_Y);

  k_split<<<512, 256, 0, stream>>>(eW, Wi, Ah, Al, Wh, Wl, AtF);
  k_u<<<256, 512, 0, stream>>>(I, Wh, Wl, out);
  // M-power chain: A^2 -> A^4 -> A^8 -> A^16 -> A^32(M1) -> A^64(M2) -> A^96(M3)
  k_mm256<<<16, 512, 0, stream>>>(AtF, Ah, Al, M2f, M2h, M2l);    // A^2
  k_mm256<<<16, 512, 0, stream>>>(M2f, M2h, M2l, M3f, M3h, M3l);  // A^4
  k_mm256<<<16, 512, 0, stream>>>(M3f, M3h, M3l, M2f, M2h, M2l);  // A^8
  k_mm256<<<16, 512, 0, stream>>>(M2f, M2h, M2l, M3f, M3h, M3l);  // A^16
  k_mm256<<<16, 512, 0, stream>>>(M3f, M3h, M3l, M1f, M1h, M1l);  // A^32
  k_mm256<<<16, 512, 0, stream>>>(M1f, M1h, M1l, M2f, M2h, M2l);  // A^64
  k_mm256<<<16, 512, 0, stream>>>(M2f, M1h, M1l, M3f, M3h, M3l);  // A^96
  k_scan<<<256, 1024, 0, stream>>>(1, Ah, Al, out, Y, S);
  k_bnd<<<64, 512, 0, stream>>>(x0, S, M1h, M1l, M2h, M2l, M3h, M3l, Y);
  k_scan<<<256, 1024, 0, stream>>>(2, Ah, Al, out, Y, S);
}